// Round 1
// baseline (889.195 us; speedup 1.0000x reference)
//
#include <hip/hip_runtime.h>
#include <hip/hip_bf16.h>
#include <stdint.h>

#define NN 50000
#define NE 800000
#define HH 128

typedef __bf16 bf16x8 __attribute__((ext_vector_type(8)));
typedef float  f32x4  __attribute__((ext_vector_type(4)));
typedef long   f8frag;   // 8 fp8 bytes = i64 MFMA operand

__device__ __forceinline__ unsigned short f2bf(float f) {
  union { float f; uint32_t u; } v; v.f = f;
  uint32_t r = v.u + 0x7FFFu + ((v.u >> 16) & 1u);
  return (unsigned short)(r >> 16);
}
#if __has_builtin(__builtin_amdgcn_cvt_pk_bf16_f32)
typedef __bf16 bf16x2 __attribute__((ext_vector_type(2)));
__device__ __forceinline__ uint32_t pack2bf(float a, float b) {
  union { bf16x2 v; uint32_t u; } t;
  t.v = __builtin_amdgcn_cvt_pk_bf16_f32(a, b);
  return t.u;
}
#else
__device__ __forceinline__ uint32_t pack2bf(float a, float b) {
  return (uint32_t)f2bf(a) | ((uint32_t)f2bf(b) << 16);
}
#endif
__device__ __forceinline__ uint8_t f2fp8(float v) {
  return (uint8_t)(__builtin_amdgcn_cvt_pk_fp8_f32(v, 0.f, 0, false) & 0xff);
}
// fast silu/sigmoid
__device__ __forceinline__ float silu_f(float x) {
  return x * __builtin_amdgcn_rcpf(1.f + __expf(-x));
}
__device__ __forceinline__ float sigm_f(float x) {
  return __builtin_amdgcn_rcpf(1.f + __expf(-x));
}

// LDS tile blocks (bf16): [rows][32 k], 16B chunk c stored at c ^ ((row>>1)&3)
__device__ __forceinline__ bf16x8 frag_ld(const short* blk, int row, int q) {
  int c = q ^ ((row >> 1) & 3);
  return *(const bf16x8*)(blk + row * 32 + c * 8);
}
// bf16 global weight frag offset (swizzled prep layout, short-indexed)
__device__ __forceinline__ int wfrag_off(int row, int q) {
  return row * 32 + ((q ^ ((row >> 1) & 3)) * 8);
}

// ---------------- weight prep ----------------
// W1f8: 3 sets (GCL0, GCL1, coord) x [9 kk][128 n][32 k] fp8 bytes, plain layout
// W2sw: 3 sets bf16 swizzled; Wn1sw/Wn2sw: 2 sets bf16 swizzled
__global__ void k_prep_weights(const float* We1, const float* We2, const float* Wn1,
                               const float* Wn2, const float* cW1, const float* cW2,
                               uint8_t* W1f8, short* W2sw, short* Wn1sw, short* Wn2sw) {
  int idx = blockIdx.x * 256 + threadIdx.x;
  if (idx < 110592) {                      // fp8 W1 (ks=265)
    int l = idx / 36864, rem = idx % 36864;
    const float* s = (l == 0) ? We1 : (l == 1) ? We1 + 33920 : cW1;
    int kkb = rem >> 12, r2 = rem & 4095;
    int n = r2 >> 5, kw = r2 & 31;
    int k = kkb * 32 + kw;
    float v = (k < 265) ? s[k * 128 + n] : 0.f;
    W1f8[idx] = f2fp8(v);
    return;
  }
  idx -= 110592;
  if (idx < 49152) {                       // bf16 W2, 3 sets, ks=128
    int l = idx >> 14, rem = idx & 16383;
    const float* s = (l == 0) ? We2 : (l == 1) ? We2 + 16384 : cW2;
    int kkb = rem >> 12, r2 = rem & 4095, n = r2 >> 5, kw = r2 & 31;
    int cp = kw >> 3, j = kw & 7, c = cp ^ ((n >> 1) & 3);
    int k = kkb * 32 + c * 8 + j;
    W2sw[(l << 14) + (rem)] = (short)f2bf(s[k * 128 + n]);
    return;
  }
  idx -= 49152;
  if (idx < 65536) {                       // bf16 Wn1, 2 sets, ks=256
    int l = idx >> 15, rem = idx & 32767;
    const float* s = Wn1 + l * 32768;
    int kkb = rem >> 12, r2 = rem & 4095, n = r2 >> 5, kw = r2 & 31;
    int cp = kw >> 3, j = kw & 7, c = cp ^ ((n >> 1) & 3);
    int k = kkb * 32 + c * 8 + j;
    Wn1sw[(l << 15) + rem] = (short)f2bf(s[k * 128 + n]);
    return;
  }
  idx -= 65536;
  if (idx < 32768) {                       // bf16 Wn2, 2 sets, ks=128
    int l = idx >> 14, rem = idx & 16383;
    const float* s = Wn2 + l * 16384;
    int kkb = rem >> 12, r2 = rem & 4095, n = r2 >> 5, kw = r2 & 31;
    int cp = kw >> 3, j = kw & 7, c = cp ^ ((n >> 1) & 3);
    int k = kkb * 32 + c * 8 + j;
    Wn2sw[(l << 14) + rem] = (short)f2bf(s[k * 128 + n]);
  }
}

// ---------------- small prep kernels ----------------
// fused: x (f32) -> Anode bf16 [node][256] low half  +  XF8 fp8 [node][128]
__global__ void k_x_prep(const float* __restrict__ x, short* __restrict__ Anode,
                         uint8_t* __restrict__ XF8) {
  int i = blockIdx.x * 256 + threadIdx.x;     // float4 index
  if (i < NN * 32) {
    float4 v = ((const float4*)x)[i];
    int r = __builtin_amdgcn_cvt_pk_fp8_f32(v.x, v.y, 0, false);
    r = __builtin_amdgcn_cvt_pk_fp8_f32(v.z, v.w, r, true);
    ((uint32_t*)XF8)[i] = (uint32_t)r;
    int node = i >> 5, c4 = (i & 31) << 2;
    ushort4 pk;
    pk.x = f2bf(v.x); pk.y = f2bf(v.y); pk.z = f2bf(v.z); pk.w = f2bf(v.w);
    *(ushort4*)(Anode + node * 256 + c4) = pk;
  }
}
__global__ void k_xf8(const float* __restrict__ src, uint8_t* __restrict__ XF8) {
  int i = blockIdx.x * 256 + threadIdx.x;
  if (i < NN * 32) {
    float4 v = ((const float4*)src)[i];
    int r = __builtin_amdgcn_cvt_pk_fp8_f32(v.x, v.y, 0, false);
    r = __builtin_amdgcn_cvt_pk_fp8_f32(v.z, v.w, r, true);
    ((uint32_t*)XF8)[i] = (uint32_t)r;
  }
}
__global__ void k_nodeprep(const float* __restrict__ agg, short* __restrict__ Anode) {
  int i = blockIdx.x * 256 + threadIdx.x;
  if (i < NN * HH) Anode[(i >> 7) * 256 + 128 + (i & 127)] = (short)f2bf(agg[i] * 0.01f);
}
// after sort: original-order streaming reads, scatter-writes into sorted slots
__global__ void k_edge_pre(const float* __restrict__ pos, const float* __restrict__ eattr,
                           const int* __restrict__ ei, const int* __restrict__ inv,
                           int* __restrict__ rowS, int* __restrict__ colS,
                           uint8_t* __restrict__ eaF8, float* __restrict__ ndS) {
  int e = blockIdx.x * 256 + threadIdx.x;
  if (e >= NE) return;
  int r = ei[e], c = ei[NE + e];
  float dx = pos[r * 3 + 0] - pos[c * 3 + 0];
  float dy = pos[r * 3 + 1] - pos[c * 3 + 1];
  float dz = pos[r * 3 + 2] - pos[c * 3 + 2];
  float d2 = dx * dx + dy * dy + dz * dz;
  float invd = __builtin_amdgcn_rcpf(sqrtf(d2) + 1.f);   // NC = 1.0
  int p = inv[e];
  rowS[p] = r;
  colS[p] = c;
  ndS[p * 3 + 0] = dx * invd;
  ndS[p * 3 + 1] = dy * invd;
  ndS[p * 3 + 2] = dz * invd;
  const float* ea = eattr + (size_t)e * 8;
  uint32_t w0 = __builtin_amdgcn_cvt_pk_fp8_f32(d2, ea[0], 0, false);
  w0 = __builtin_amdgcn_cvt_pk_fp8_f32(ea[1], ea[2], w0, true);
  uint32_t w1 = __builtin_amdgcn_cvt_pk_fp8_f32(ea[3], ea[4], 0, false);
  w1 = __builtin_amdgcn_cvt_pk_fp8_f32(ea[5], ea[6], w1, true);
  uint32_t w2 = __builtin_amdgcn_cvt_pk_fp8_f32(ea[7], 0.f, 0, false);
  uint4 v = {w0, w1, w2, 0u};
  *(uint4*)(eaF8 + (size_t)p * 16) = v;
}
__global__ void k_pos_final(const float* __restrict__ pos, const float* __restrict__ mask,
                            const float* __restrict__ pagg, float* __restrict__ out) {
  int i = blockIdx.x * 256 + threadIdx.x;
  if (i < NN * 3) out[i] = pos[i] + pagg[i] * 0.01f * mask[i / 3];
}

// ---------------- CSR sort of edges by destination row ----------------
__global__ void k_hist(const int* __restrict__ ei, int* __restrict__ cnt) {
  int e = blockIdx.x * 256 + threadIdx.x;
  if (e < NE) atomicAdd(&cnt[ei[e]], 1);
}
__global__ void k_scan_block(const int* __restrict__ cnt, int* __restrict__ offs,
                             int* __restrict__ bsum) {
  __shared__ int s[256];
  int i = blockIdx.x * 256 + threadIdx.x;
  int v = (i < NN) ? cnt[i] : 0;
  s[threadIdx.x] = v;
  __syncthreads();
#pragma unroll
  for (int d = 1; d < 256; d <<= 1) {
    int t = (threadIdx.x >= d) ? s[threadIdx.x - d] : 0;
    __syncthreads();
    s[threadIdx.x] += t;
    __syncthreads();
  }
  if (i < NN) offs[i] = s[threadIdx.x] - v;
  if (threadIdx.x == 255) bsum[blockIdx.x] = s[255];
}
__global__ void k_scan_top(int* __restrict__ bsum) {
  __shared__ int s[256];
  int v = (threadIdx.x < 196) ? bsum[threadIdx.x] : 0;
  s[threadIdx.x] = v;
  __syncthreads();
#pragma unroll
  for (int d = 1; d < 256; d <<= 1) {
    int t = (threadIdx.x >= d) ? s[threadIdx.x - d] : 0;
    __syncthreads();
    s[threadIdx.x] += t;
    __syncthreads();
  }
  if (threadIdx.x < 196) bsum[threadIdx.x] = s[threadIdx.x] - v;
}
__global__ void k_scan_add(int* __restrict__ offs, const int* __restrict__ bsum) {
  int i = blockIdx.x * 256 + threadIdx.x;
  if (i < NN) offs[i] += bsum[blockIdx.x];
}
__global__ void k_scatter(const int* __restrict__ ei, int* __restrict__ offs,
                          int* __restrict__ inv) {
  int e = blockIdx.x * 256 + threadIdx.x;
  if (e < NE) inv[e] = atomicAdd(&offs[ei[e]], 1);
}

// ---------------- fused edge/coord MLP GEMM (edges presorted by row) ----------------
// GEMM1 in fp8 (gathered XF8/eaF8 + fp8 W1), GEMM2/h1/segment-sum in bf16.
// TRANSPOSED MFMA: A=W-frag, B=he-frag => D[chan][edge] (lane=edge).
// launch_bounds(256,6): LDS 17.9KB*6=107KB fits; VGPR cap 512/6~=85 fits
// arch(48)+acc(~32) without spill. (256,4) capped occupancy at 50% -- the
// kernel is gather-latency-bound, needs the extra waves.
template <int COORD>
__global__ __launch_bounds__(256, 6) void k_edge_gemm(
    const uint8_t* __restrict__ XF8, const uint8_t* __restrict__ eaF8,
    const int* __restrict__ rowS, const int* __restrict__ colS,
    const uint8_t* __restrict__ W1f8, const short* __restrict__ W2l,
    const float* __restrict__ b1, const float* __restrict__ b2,
    const float* __restrict__ wred, const float* __restrict__ batt,
    const float* __restrict__ ndS, float* outAcc) {
  __shared__ __align__(16) short A2s[8192];  // h1^T 4x[64e][32c]; then M 2x[128c][32e]
  __shared__ float redp[64][2];
  __shared__ float redv[64];
  __shared__ int srow[64];
  __shared__ __align__(8) unsigned char srunS[64];
  __shared__ int runrowS[64];
  __shared__ int cntS[1];

  const int tid = threadIdx.x;
  const int lane = tid & 63;
  const int w = tid >> 6;
  const int ln = lane & 15, q = lane >> 4;
  const int wm = w >> 1, wn = w & 1;
  const int tile = blockIdx.x;

  if (tid < 64) srow[tid] = rowS[tile * 64 + tid];
  __syncthreads();

  // ---- segmented-run scan over sorted rows (wave 0 only) ----
  bool is_start = (tid < 64) && (tid == 0 || srow[tid] != srow[tid - 1]);
  unsigned long long bmask = __ballot(is_start);
  if (tid == 0) cntS[0] = __popcll(bmask);
  if (tid < 64) {
    int run = __popcll(bmask & ((1ull << lane) - 1ull)) + (is_start ? 1 : 0) - 1;
    srunS[tid] = (unsigned char)run;
    if (is_start) runrowS[run] = srow[tid];
  }
  // (published by epilogue1's barrier; read only after GEMM2)

  // per-lane fragment sources (fp8: 8B per frag)
  const int e0 = wm * 32 + ln, e1 = e0 + 16;
  const size_t rb0 = (size_t)srow[e0] * 128, rb1 = (size_t)srow[e1] * 128;
  const size_t cb0 = (size_t)colS[tile * 64 + e0] * 128;
  const size_t cb1 = (size_t)colS[tile * 64 + e1] * 128;
  const size_t ea0 = (size_t)(tile * 64 + e0) * 16 + (q & 1) * 8;
  const size_t ea1 = (size_t)(tile * 64 + e1) * 16 + (q & 1) * 8;
  int wofs8[4], wofs[4];
#pragma unroll
  for (int i = 0; i < 4; ++i) {
    wofs8[i] = (wn * 64 + i * 16 + ln) * 32 + q * 8;      // fp8 bytes
    wofs[i] = wfrag_off(wn * 64 + i * 16 + ln, q);        // bf16 shorts
  }

  f32x4 acc[4][2];                           // [chan-tile ni][edge-tile mi]
  const f32x4 zero4 = {0.f, 0.f, 0.f, 0.f};
#pragma unroll
  for (int ni = 0; ni < 4; ++ni)
#pragma unroll
    for (int mi = 0; mi < 2; ++mi) acc[ni][mi] = zero4;

  // -------- GEMM1 (fp8): h1^T[128c x 64e] = W1^T(A) x he^T(B), barrier-free --------
#pragma unroll
  for (int kk = 0; kk < 9; ++kk) {
    f8frag wf[4], hf[2];
#pragma unroll
    for (int i = 0; i < 4; ++i) wf[i] = *(const f8frag*)(W1f8 + kk * 4096 + wofs8[i]);
    if (kk < 4) {
      hf[0] = *(const f8frag*)(XF8 + rb0 + kk * 32 + q * 8);
      hf[1] = *(const f8frag*)(XF8 + rb1 + kk * 32 + q * 8);
    } else if (kk < 8) {
      hf[0] = *(const f8frag*)(XF8 + cb0 + (kk - 4) * 32 + q * 8);
      hf[1] = *(const f8frag*)(XF8 + cb1 + (kk - 4) * 32 + q * 8);
    } else {
      hf[0] = (q < 2) ? *(const f8frag*)(eaF8 + ea0) : 0L;
      hf[1] = (q < 2) ? *(const f8frag*)(eaF8 + ea1) : 0L;
    }
#pragma unroll
    for (int ni = 0; ni < 4; ++ni)
#pragma unroll
      for (int mi = 0; mi < 2; ++mi)
        acc[ni][mi] = __builtin_amdgcn_mfma_f32_16x16x32_fp8_fp8(wf[ni], hf[mi], acc[ni][mi], 0, 0, 0);
  }

  // -------- epilogue1: silu(h1+b1) -> A2s bf16 [edge][chan] via packed b64 writes --------
  float4 b1v[4];
#pragma unroll
  for (int ni = 0; ni < 4; ++ni)
    b1v[ni] = *(const float4*)(b1 + wn * 64 + ni * 16 + q * 4);
#pragma unroll
  for (int ni = 0; ni < 4; ++ni) {
    int cb = wn * 64 + ni * 16 + q * 4;            // 4 consecutive chans per lane
    int kkb = cb >> 5, cc = (cb >> 3) & 3, j0 = cb & 7;
#pragma unroll
    for (int mi = 0; mi < 2; ++mi) {
      int edge = wm * 32 + mi * 16 + ln;
      int addr = kkb * 2048 + edge * 32 + ((cc ^ ((edge >> 1) & 3)) * 8) + j0;
      uint2 pk;
      pk.x = pack2bf(silu_f(acc[ni][mi][0] + b1v[ni].x), silu_f(acc[ni][mi][1] + b1v[ni].y));
      pk.y = pack2bf(silu_f(acc[ni][mi][2] + b1v[ni].z), silu_f(acc[ni][mi][3] + b1v[ni].w));
      *(uint2*)(A2s + addr) = pk;
    }
  }
  __syncthreads();

  // -------- GEMM2 (bf16): M^T[128c2 x 64e] = W2^T(A) x h1^T(B), barrier-free --------
  f32x4 acc2[4][2];
#pragma unroll
  for (int ni = 0; ni < 4; ++ni)
#pragma unroll
    for (int mi = 0; mi < 2; ++mi) acc2[ni][mi] = zero4;
#pragma unroll
  for (int kk = 0; kk < 4; ++kk) {
    bf16x8 wf[4], hf[2];
#pragma unroll
    for (int i = 0; i < 4; ++i) wf[i] = *(const bf16x8*)(W2l + kk * 4096 + wofs[i]);
#pragma unroll
    for (int i = 0; i < 2; ++i) hf[i] = frag_ld(A2s + kk * 2048, wm * 32 + i * 16 + ln, q);
#pragma unroll
    for (int ni = 0; ni < 4; ++ni)
#pragma unroll
      for (int mi = 0; mi < 2; ++mi)
        acc2[ni][mi] = __builtin_amdgcn_mfma_f32_16x16x32_bf16(wf[ni], hf[mi], acc2[ni][mi], 0, 0, 0);
  }

  // -------- epilogue2: silu + attention/phi dot (mostly in-lane) --------
  float4 b2v[4], wv[4];
#pragma unroll
  for (int ni = 0; ni < 4; ++ni) {
    b2v[ni] = *(const float4*)(b2 + wn * 64 + ni * 16 + q * 4);
    wv[ni]  = *(const float4*)(wred + wn * 64 + ni * 16 + q * 4);
  }
  float p[2] = {0.f, 0.f};
#pragma unroll
  for (int ni = 0; ni < 4; ++ni)
#pragma unroll
    for (int mi = 0; mi < 2; ++mi)
#pragma unroll
      for (int r = 0; r < 4; ++r) {
        float v = silu_f(acc2[ni][mi][r] + ((const float*)&b2v[ni])[r]);
        acc2[ni][mi][r] = v;
        p[mi] += v * ((const float*)&wv[ni])[r];
      }
#pragma unroll
  for (int mi = 0; mi < 2; ++mi) {
    p[mi] += __shfl_xor(p[mi], 16, 64);
    p[mi] += __shfl_xor(p[mi], 32, 64);
  }
  if (lane < 16) {
#pragma unroll
    for (int mi = 0; mi < 2; ++mi) redp[wm * 32 + mi * 16 + ln][wn] = p[mi];
  }
  __syncthreads();   // redp ready; all waves done with A2s (GEMM2)

  if (COORD == 0) {
    if (tid < 64) redv[tid] = sigm_f(redp[tid][0] + redp[tid][1] + batt[0]);
    __syncthreads();
    // M-tile 2x[128 chan][32 edge] swizzled blocks (B-operand layout for S-GEMM)
    float attv[2] = {redv[wm * 32 + ln], redv[wm * 32 + 16 + ln]};
#pragma unroll
    for (int ni = 0; ni < 4; ++ni)
#pragma unroll
      for (int mi = 0; mi < 2; ++mi) {
        int eb = mi * 16 + ln;
        int cE = (eb >> 3) & 3, jE = eb & 7;
#pragma unroll
        for (int r = 0; r < 4; ++r) {
          int chan2 = wn * 64 + ni * 16 + q * 4 + r;
          int addr = wm * 4096 + chan2 * 32 + ((cE ^ ((chan2 >> 1) & 3)) * 8) + jE;
          union { float f; uint32_t u; } vv;
          vv.f = acc2[ni][mi][r] * attv[mi];
          A2s[addr] = (short)((vv.u + 0x8000u) >> 16);   // round-half-up to bf16
        }
      }
    __syncthreads();
    // segment-sum via MFMA: agg[run][chan] = S[run][edge] @ M[edge][chan]
    const int nruns = cntS[0];
    bf16x8 bfrg[2][2];
#pragma unroll
    for (int kk = 0; kk < 2; ++kk)
#pragma unroll
      for (int ni = 0; ni < 2; ++ni)
        bfrg[kk][ni] = frag_ld(A2s + kk * 4096, w * 32 + ni * 16 + ln, q);
    const int npass = (nruns + 15) >> 4;
    for (int pp = 0; pp < npass; ++pp) {
      const unsigned int base = pp * 16;
      f32x4 a3c[2] = {zero4, zero4};
#pragma unroll
      for (int kk = 0; kk < 2; ++kk) {
        uint2 sb = *(const uint2*)(srunS + kk * 32 + q * 8);
        union { short s[8]; bf16x8 v; } af;
#pragma unroll
        for (int j = 0; j < 4; ++j)
          af.s[j] = (((sb.x >> (8 * j)) & 255u) == base + (unsigned)ln) ? (short)0x3F80 : (short)0;
#pragma unroll
        for (int j = 0; j < 4; ++j)
          af.s[4 + j] = (((sb.y >> (8 * j)) & 255u) == base + (unsigned)ln) ? (short)0x3F80 : (short)0;
        a3c[0] = __builtin_amdgcn_mfma_f32_16x16x32_bf16(af.v, bfrg[kk][0], a3c[0], 0, 0, 0);
        a3c[1] = __builtin_amdgcn_mfma_f32_16x16x32_bf16(af.v, bfrg[kk][1], a3c[1], 0, 0, 0);
      }
#pragma unroll
      for (int ni = 0; ni < 2; ++ni)
#pragma unroll
        for (int r = 0; r < 4; ++r) {
          int run = (int)base + q * 4 + r;
          if (run < nruns) {
            int rw = runrowS[run];
            atomicAdd(&outAcc[(size_t)rw * 128 + (w * 32 + ni * 16 + ln)], a3c[ni][r]);
          }
        }
    }
  } else {
    float* ndl = (float*)A2s;   // reuse: [64][3]
    if (tid < 64) {
      float phi = redp[tid][0] + redp[tid][1];
      ndl[tid * 3 + 0] = ndS[(size_t)(tile * 64 + tid) * 3 + 0] * phi;
      ndl[tid * 3 + 1] = ndS[(size_t)(tile * 64 + tid) * 3 + 1] * phi;
      ndl[tid * 3 + 2] = ndS[(size_t)(tile * 64 + tid) * 3 + 2] * phi;
    }
    __syncthreads();
    if (is_start) {   // run-start walkers (tid<64 implied)
      int myrow = srow[tid];
      float s0 = 0.f, s1 = 0.f, s2 = 0.f;
      for (int j = tid; j < 64 && srow[j] == myrow; ++j) {
        s0 += ndl[j * 3 + 0];
        s1 += ndl[j * 3 + 1];
        s2 += ndl[j * 3 + 2];
      }
      atomicAdd(&outAcc[myrow * 3 + 0], s0);
      atomicAdd(&outAcc[myrow * 3 + 1], s1);
      atomicAdd(&outAcc[myrow * 3 + 2], s2);
    }
  }
}

// ---------------- node MLP GEMM (residual update, 128-node tiles, bf16) ----------------
__global__ __launch_bounds__(256) void k_node_gemm(
    short* Anode, const short* __restrict__ Wn1l, const short* __restrict__ Wn2l,
    const float* __restrict__ b1, const float* __restrict__ b2,
    const float* __restrict__ xres, float* __restrict__ xout) {
  __shared__ short A2s[4 * 4096];

  const int tid = threadIdx.x;
  const int lane = tid & 63;
  const int w = tid >> 6;
  const int ln = lane & 15, q = lane >> 4;
  const int wm = w >> 1, wn = w & 1;
  const int tile = blockIdx.x;

  size_t nbase[4];
  int wofs[4];
#pragma unroll
  for (int i = 0; i < 4; ++i) {
    int node = tile * 128 + wm * 64 + i * 16 + ln;
    nbase[i] = (size_t)(node < NN ? node : (NN - 1)) * 256;
    wofs[i] = wfrag_off(wn * 64 + i * 16 + ln, q);
  }

  f32x4 acc[4][4];
  const f32x4 zero4 = {0.f, 0.f, 0.f, 0.f};
#pragma unroll
  for (int mi = 0; mi < 4; ++mi)
#pragma unroll
    for (int ni = 0; ni < 4; ++ni) acc[mi][ni] = zero4;

#pragma unroll
  for (int kk = 0; kk < 8; ++kk) {
    bf16x8 af[4], bfr[4];
#pragma unroll
    for (int i = 0; i < 4; ++i) af[i] = *(const bf16x8*)(Anode + nbase[i] + kk * 32 + q * 8);
#pragma unroll
    for (int i = 0; i < 4; ++i) bfr[i] = *(const bf16x8*)(Wn1l + kk * 4096 + wofs[i]);
#pragma unroll
    for (int mi = 0; mi < 4; ++mi)
#pragma unroll
      for (int ni = 0; ni < 4; ++ni)
        acc[mi][ni] = __builtin_amdgcn_mfma_f32_16x16x32_bf16(af[mi], bfr[ni], acc[mi][ni], 0, 0, 0);
  }

  float b1v[4];
#pragma unroll
  for (int ni = 0; ni < 4; ++ni) b1v[ni] = b1[wn * 64 + ni * 16 + ln];
#pragma unroll
  for (int mi = 0; mi < 4; ++mi)
#pragma unroll
    for (int ni = 0; ni < 4; ++ni) {
      int chan = wn * 64 + ni * 16 + ln;
      int kkb = chan >> 5, c = (chan >> 3) & 3, jj = chan & 7;
#pragma unroll
      for (int r = 0; r < 4; ++r) {
        int m = wm * 64 + mi * 16 + q * 4 + r;
        float v = silu_f(acc[mi][ni][r] + b1v[ni]);
        A2s[kkb * 4096 + m * 32 + ((c ^ ((m >> 1) & 3)) * 8) + jj] = (short)f2bf(v);
      }
    }
  __syncthreads();

  f32x4 acc2[4][4];
#pragma unroll
  for (int mi = 0; mi < 4; ++mi)
#pragma unroll
    for (int ni = 0; ni < 4; ++ni) acc2[mi][ni] = zero4;
#pragma unroll
  for (int kk = 0; kk < 4; ++kk) {
    bf16x8 af[4], bfr[4];
#pragma unroll
    for (int i = 0; i < 4; ++i) af[i] = frag_ld(A2s + kk * 4096, wm * 64 + i * 16 + ln, q);
#pragma unroll
    for (int i = 0; i < 4; ++i) bfr[i] = *(const bf16x8*)(Wn2l + kk * 4096 + wofs[i]);
#pragma unroll
    for (int mi = 0; mi < 4; ++mi)
#pragma unroll
      for (int ni = 0; ni < 4; ++ni)
        acc2[mi][ni] = __builtin_amdgcn_mfma_f32_16x16x32_bf16(af[mi], bfr[ni], acc2[mi][ni], 0, 0, 0);
  }

  float b2v[4];
#pragma unroll
  for (int ni = 0; ni < 4; ++ni) b2v[ni] = b2[wn * 64 + ni * 16 + ln];
#pragma unroll
  for (int mi = 0; mi < 4; ++mi)
#pragma unroll
    for (int r = 0; r < 4; ++r) {
      int m = wm * 64 + mi * 16 + q * 4 + r;
      int node = tile * 128 + m;
      if (node < NN) {
#pragma unroll
        for (int ni = 0; ni < 4; ++ni) {
          int chan = wn * 64 + ni * 16 + ln;
          float v = acc2[mi][ni][r] + b2v[ni] + xres[(size_t)node * 128 + chan];
          xout[(size_t)node * 128 + chan] = v;
          Anode[(size_t)node * 256 + chan] = (short)f2bf(v);
        }
      }
    }
}

extern "C" void kernel_launch(void* const* d_in, const int* in_sizes, int n_in,
                              void* d_out, int out_size, void* d_ws, size_t ws_size,
                              hipStream_t stream) {
  const float* x    = (const float*)d_in[0];
  const float* pos  = (const float*)d_in[1];
  const float* mask = (const float*)d_in[2];
  const float* eattr= (const float*)d_in[3];
  const int*   ei   = (const int*)d_in[4];
  const float* We1  = (const float*)d_in[5];
  const float* be1  = (const float*)d_in[6];
  const float* We2  = (const float*)d_in[7];
  const float* be2  = (const float*)d_in[8];
  const float* Watt = (const float*)d_in[9];
  const float* batt = (const float*)d_in[10];
  const float* Wn1  = (const float*)d_in[11];
  const float* bn1  = (const float*)d_in[12];
  const float* Wn2  = (const float*)d_in[13];
  const float* bn2  = (const float*)d_in[14];
  const float* cW1  = (const float*)d_in[15];
  const float* cb1  = (const float*)d_in[16];
  const float* cW2  = (const float*)d_in[17];
  const float* cb2  = (const float*)d_in[18];
  const float* cW3  = (const float*)d_in[19];

  char* p = (char*)d_ws;
  auto carve = [&](size_t bytes) { char* r = p; p += (bytes + 511) & ~(size_t)511; return r; };
  short*   Anode = (short*)carve((size_t)NN * 256 * 2);
  uint8_t* XF8   = (uint8_t*)carve((size_t)NN * 128);
  uint8_t* eaF8  = (uint8_t*)carve((size_t)NE * 16 + 256);
  int*     rowS  = (int*)carve((size_t)NE * 4);
  int*     colS  = (int*)carve((size_t)NE * 4);
  float*   ndS   = (float*)carve((size_t)NE * 3 * 4);
  float*   agg   = (float*)carve((size_t)NN * 128 * 4);
  float*   xcur  = (float*)carve((size_t)NN * 128 * 4);
  float*   pagg  = (float*)carve((size_t)NN * 3 * 4);
  uint8_t* W1f8  = (uint8_t*)carve(3 * 36864);
  short*   W2sw  = (short*)carve(3 * 16384 * 2);
  short*   Wn1sw = (short*)carve(2 * 32768 * 2);
  short*   Wn2sw = (short*)carve(2 * 16384 * 2);
  int*     cnt   = (int*)carve((size_t)NN * 4);
  int*     offs  = (int*)carve((size_t)NN * 4);
  int*     bsum  = (int*)carve(256 * 4);
  int*     inv   = (int*)carve((size_t)NE * 4);

  float* xout_f = (float*)d_out;        // N*128
  float* pout_f = xout_f + NN * 128;    // N*3

  k_prep_weights<<<1008, 256, 0, stream>>>(We1, We2, Wn1, Wn2, cW1, cW2,
                                           W1f8, W2sw, Wn1sw, Wn2sw);
  k_x_prep<<<6250, 256, 0, stream>>>(x, Anode, XF8);

  // build row-sorted edge permutation (CSR order) -> inv[e] = sorted slot
  hipMemsetAsync(cnt, 0, (size_t)NN * 4, stream);
  k_hist<<<3125, 256, 0, stream>>>(ei, cnt);
  k_scan_block<<<196, 256, 0, stream>>>(cnt, offs, bsum);
  k_scan_top<<<1, 256, 0, stream>>>(bsum);
  k_scan_add<<<196, 256, 0, stream>>>(offs, bsum);
  k_scatter<<<3125, 256, 0, stream>>>(ei, offs, inv);
  k_edge_pre<<<3125, 256, 0, stream>>>(pos, eattr, ei, inv, rowS, colS, eaF8, ndS);

  for (int l = 0; l < 2; ++l) {
    hipMemsetAsync(agg, 0, (size_t)NN * 128 * 4, stream);
    k_edge_gemm<0><<<12500, 256, 0, stream>>>(XF8, eaF8, rowS, colS,
        W1f8 + l * 36864, W2sw + l * 16384, be1 + l * 128, be2 + l * 128,
        Watt + l * 128, batt + l, (const float*)nullptr, agg);
    k_nodeprep<<<25000, 256, 0, stream>>>(agg, Anode);
    k_node_gemm<<<391, 256, 0, stream>>>(Anode,
        Wn1sw + l * 32768, Wn2sw + l * 16384, bn1 + l * 128, bn2 + l * 128,
        l == 0 ? x : xcur, l == 0 ? xcur : xout_f);
    k_xf8<<<6250, 256, 0, stream>>>(l == 0 ? xcur : xout_f, XF8);
  }
  hipMemsetAsync(pagg, 0, (size_t)NN * 3 * 4, stream);
  k_edge_gemm<1><<<12500, 256, 0, stream>>>(XF8, eaF8, rowS, colS,
      W1f8 + 2 * 36864, W2sw + 2 * 16384, cb1, cb2, cW3, (const float*)nullptr, ndS, pagg);
  k_pos_final<<<587, 256, 0, stream>>>(pos, mask, pagg, pout_f);
}

// Round 2
// 799.815 us; speedup vs baseline: 1.1118x; 1.1118x over previous
//
#include <hip/hip_runtime.h>
#include <hip/hip_bf16.h>
#include <stdint.h>

#define NN 50000
#define NE 800000
#define HH 128

typedef __bf16 bf16x8 __attribute__((ext_vector_type(8)));
typedef float  f32x4  __attribute__((ext_vector_type(4)));
typedef long   f8frag;   // 8 fp8 bytes = i64 MFMA operand

__device__ __forceinline__ unsigned short f2bf(float f) {
  union { float f; uint32_t u; } v; v.f = f;
  uint32_t r = v.u + 0x7FFFu + ((v.u >> 16) & 1u);
  return (unsigned short)(r >> 16);
}
__device__ __forceinline__ float b2f(unsigned short u) {
  union { float f; uint32_t u; } v; v.u = (uint32_t)u << 16; return v.f;
}
#if __has_builtin(__builtin_amdgcn_cvt_pk_bf16_f32)
typedef __bf16 bf16x2 __attribute__((ext_vector_type(2)));
__device__ __forceinline__ uint32_t pack2bf(float a, float b) {
  union { bf16x2 v; uint32_t u; } t;
  t.v = __builtin_amdgcn_cvt_pk_bf16_f32(a, b);
  return t.u;
}
#else
__device__ __forceinline__ uint32_t pack2bf(float a, float b) {
  return (uint32_t)f2bf(a) | ((uint32_t)f2bf(b) << 16);
}
#endif
__device__ __forceinline__ uint8_t f2fp8(float v) {
  return (uint8_t)(__builtin_amdgcn_cvt_pk_fp8_f32(v, 0.f, 0, false) & 0xff);
}
// fast silu/sigmoid
__device__ __forceinline__ float silu_f(float x) {
  return x * __builtin_amdgcn_rcpf(1.f + __expf(-x));
}
__device__ __forceinline__ float sigm_f(float x) {
  return __builtin_amdgcn_rcpf(1.f + __expf(-x));
}

// LDS tile blocks (bf16): [rows][32 k], 16B chunk c stored at c ^ ((row>>1)&3)
__device__ __forceinline__ bf16x8 frag_ld(const short* blk, int row, int q) {
  int c = q ^ ((row >> 1) & 3);
  return *(const bf16x8*)(blk + row * 32 + c * 8);
}
// bf16 global weight frag offset (swizzled prep layout, short-indexed)
__device__ __forceinline__ int wfrag_off(int row, int q) {
  return row * 32 + ((q ^ ((row >> 1) & 3)) * 8);
}

// ---------------- weight prep ----------------
// W1f8: 3 sets x [9 kk][128 n][32 k] fp8 (only kk=8 / ea block used by edge kernel now)
// W2sw: 3 sets bf16 swizzled; Wn1sw/Wn2sw: 2 sets bf16 swizzled
// W1csw: 3 sets x [4 kk][256 n][32 k] bf16 swizzled  (Wcat[k][n'] : n'<128 -> W1[k][n'],
//        n'>=128 -> W1[128+k][n'-128]) for the per-node H1 precompute GEMM
__global__ void k_prep_weights(const float* We1, const float* We2, const float* Wn1,
                               const float* Wn2, const float* cW1, const float* cW2,
                               uint8_t* W1f8, short* W2sw, short* Wn1sw, short* Wn2sw,
                               short* W1csw) {
  int idx = blockIdx.x * 256 + threadIdx.x;
  if (idx < 110592) {                      // fp8 W1 (ks=265)
    int l = idx / 36864, rem = idx % 36864;
    const float* s = (l == 0) ? We1 : (l == 1) ? We1 + 33920 : cW1;
    int kkb = rem >> 12, r2 = rem & 4095;
    int n = r2 >> 5, kw = r2 & 31;
    int k = kkb * 32 + kw;
    float v = (k < 265) ? s[k * 128 + n] : 0.f;
    W1f8[idx] = f2fp8(v);
    return;
  }
  idx -= 110592;
  if (idx < 49152) {                       // bf16 W2, 3 sets, ks=128
    int l = idx >> 14, rem = idx & 16383;
    const float* s = (l == 0) ? We2 : (l == 1) ? We2 + 16384 : cW2;
    int kkb = rem >> 12, r2 = rem & 4095, n = r2 >> 5, kw = r2 & 31;
    int cp = kw >> 3, j = kw & 7, c = cp ^ ((n >> 1) & 3);
    int k = kkb * 32 + c * 8 + j;
    W2sw[(l << 14) + (rem)] = (short)f2bf(s[k * 128 + n]);
    return;
  }
  idx -= 49152;
  if (idx < 65536) {                       // bf16 Wn1, 2 sets, ks=256
    int l = idx >> 15, rem = idx & 32767;
    const float* s = Wn1 + l * 32768;
    int kkb = rem >> 12, r2 = rem & 4095, n = r2 >> 5, kw = r2 & 31;
    int cp = kw >> 3, j = kw & 7, c = cp ^ ((n >> 1) & 3);
    int k = kkb * 32 + c * 8 + j;
    Wn1sw[(l << 15) + rem] = (short)f2bf(s[k * 128 + n]);
    return;
  }
  idx -= 65536;
  if (idx < 32768) {                       // bf16 Wn2, 2 sets, ks=128
    int l = idx >> 14, rem = idx & 16383;
    const float* s = Wn2 + l * 16384;
    int kkb = rem >> 12, r2 = rem & 4095, n = r2 >> 5, kw = r2 & 31;
    int cp = kw >> 3, j = kw & 7, c = cp ^ ((n >> 1) & 3);
    int k = kkb * 32 + c * 8 + j;
    Wn2sw[(l << 14) + rem] = (short)f2bf(s[k * 128 + n]);
    return;
  }
  idx -= 32768;
  if (idx < 98304) {                       // bf16 W1cat, 3 sets, [4kk][256n][32k]
    int l = idx / 32768, rem = idx % 32768;
    const float* s = (l == 0) ? We1 : (l == 1) ? We1 + 33920 : cW1;
    int kkb = rem >> 13, r2 = rem & 8191, n = r2 >> 5, kw = r2 & 31;
    int cp = kw >> 3, j = kw & 7, c = cp ^ ((n >> 1) & 3);
    int k = kkb * 32 + c * 8 + j;          // 0..127
    float v = (n < 128) ? s[k * 128 + n] : s[(128 + k) * 128 + (n - 128)];
    W1csw[l * 32768 + rem] = (short)f2bf(v);
  }
}

// ---------------- small prep kernels ----------------
// x (f32) -> Anode bf16 [node][256] low half
__global__ void k_x_prep(const float* __restrict__ x, short* __restrict__ Anode) {
  int i = blockIdx.x * 256 + threadIdx.x;     // float4 index
  if (i < NN * 32) {
    float4 v = ((const float4*)x)[i];
    int node = i >> 5, c4 = (i & 31) << 2;
    ushort4 pk;
    pk.x = f2bf(v.x); pk.y = f2bf(v.y); pk.z = f2bf(v.z); pk.w = f2bf(v.w);
    *(ushort4*)(Anode + node * 256 + c4) = pk;
  }
}
__global__ void k_nodeprep(const float* __restrict__ agg, short* __restrict__ Anode) {
  int i = blockIdx.x * 256 + threadIdx.x;
  if (i < NN * HH) Anode[(i >> 7) * 256 + 128 + (i & 127)] = (short)f2bf(agg[i] * 0.01f);
}
// after sort: original-order streaming reads, scatter-writes into sorted slots
__global__ void k_edge_pre(const float* __restrict__ pos, const float* __restrict__ eattr,
                           const int* __restrict__ ei, const int* __restrict__ inv,
                           int* __restrict__ rowS, int* __restrict__ colS,
                           uint8_t* __restrict__ eaF8, float* __restrict__ ndS) {
  int e = blockIdx.x * 256 + threadIdx.x;
  if (e >= NE) return;
  int r = ei[e], c = ei[NE + e];
  float dx = pos[r * 3 + 0] - pos[c * 3 + 0];
  float dy = pos[r * 3 + 1] - pos[c * 3 + 1];
  float dz = pos[r * 3 + 2] - pos[c * 3 + 2];
  float d2 = dx * dx + dy * dy + dz * dz;
  float invd = __builtin_amdgcn_rcpf(sqrtf(d2) + 1.f);   // NC = 1.0
  int p = inv[e];
  rowS[p] = r;
  colS[p] = c;
  ndS[p * 3 + 0] = dx * invd;
  ndS[p * 3 + 1] = dy * invd;
  ndS[p * 3 + 2] = dz * invd;
  const float* ea = eattr + (size_t)e * 8;
  uint32_t w0 = __builtin_amdgcn_cvt_pk_fp8_f32(d2, ea[0], 0, false);
  w0 = __builtin_amdgcn_cvt_pk_fp8_f32(ea[1], ea[2], w0, true);
  uint32_t w1 = __builtin_amdgcn_cvt_pk_fp8_f32(ea[3], ea[4], 0, false);
  w1 = __builtin_amdgcn_cvt_pk_fp8_f32(ea[5], ea[6], w1, true);
  uint32_t w2 = __builtin_amdgcn_cvt_pk_fp8_f32(ea[7], 0.f, 0, false);
  uint4 v = {w0, w1, w2, 0u};
  *(uint4*)(eaF8 + (size_t)p * 16) = v;
}
__global__ void k_pos_final(const float* __restrict__ pos, const float* __restrict__ mask,
                            const float* __restrict__ pagg, float* __restrict__ out) {
  int i = blockIdx.x * 256 + threadIdx.x;
  if (i < NN * 3) out[i] = pos[i] + pagg[i] * 0.01f * mask[i / 3];
}

// ---------------- CSR sort of edges by destination row ----------------
__global__ void k_hist(const int* __restrict__ ei, int* __restrict__ cnt) {
  int e = blockIdx.x * 256 + threadIdx.x;
  if (e < NE) atomicAdd(&cnt[ei[e]], 1);
}
__global__ void k_scan_block(const int* __restrict__ cnt, int* __restrict__ offs,
                             int* __restrict__ bsum) {
  __shared__ int s[256];
  int i = blockIdx.x * 256 + threadIdx.x;
  int v = (i < NN) ? cnt[i] : 0;
  s[threadIdx.x] = v;
  __syncthreads();
#pragma unroll
  for (int d = 1; d < 256; d <<= 1) {
    int t = (threadIdx.x >= d) ? s[threadIdx.x - d] : 0;
    __syncthreads();
    s[threadIdx.x] += t;
    __syncthreads();
  }
  if (i < NN) offs[i] = s[threadIdx.x] - v;
  if (threadIdx.x == 255) bsum[blockIdx.x] = s[255];
}
__global__ void k_scan_top(int* __restrict__ bsum) {
  __shared__ int s[256];
  int v = (threadIdx.x < 196) ? bsum[threadIdx.x] : 0;
  s[threadIdx.x] = v;
  __syncthreads();
#pragma unroll
  for (int d = 1; d < 256; d <<= 1) {
    int t = (threadIdx.x >= d) ? s[threadIdx.x - d] : 0;
    __syncthreads();
    s[threadIdx.x] += t;
    __syncthreads();
  }
  if (threadIdx.x < 196) bsum[threadIdx.x] = s[threadIdx.x] - v;
}
__global__ void k_scan_add(int* __restrict__ offs, const int* __restrict__ bsum) {
  int i = blockIdx.x * 256 + threadIdx.x;
  if (i < NN) offs[i] += bsum[blockIdx.x];
}
__global__ void k_scatter(const int* __restrict__ ei, int* __restrict__ offs,
                          int* __restrict__ inv) {
  int e = blockIdx.x * 256 + threadIdx.x;
  if (e < NE) inv[e] = atomicAdd(&offs[ei[e]], 1);
}

// ---------------- per-node H1 precompute: H1RC[node][256] = x @ W1cat (+b1 on low half) --
// 64 nodes/block, 4 waves; wave w owns 64 output chans (w*64..+63).
__global__ __launch_bounds__(256) void k_h1(
    const short* __restrict__ Anode, const short* __restrict__ W1c,
    const float* __restrict__ b1, short* __restrict__ H1RC) {
  const int tid = threadIdx.x, lane = tid & 63, w = tid >> 6;
  const int ln = lane & 15, q = lane >> 4;
  const int tile = blockIdx.x;
  size_t nbase[4];
  int wofs[4];
#pragma unroll
  for (int i = 0; i < 4; ++i) {
    int node = tile * 64 + i * 16 + ln;
    nbase[i] = (size_t)(node < NN ? node : (NN - 1)) * 256;
    int row = w * 64 + i * 16 + ln;
    wofs[i] = row * 32 + ((q ^ ((row >> 1) & 3)) * 8);
  }
  f32x4 acc[4][4];
  const f32x4 zero4 = {0.f, 0.f, 0.f, 0.f};
#pragma unroll
  for (int mi = 0; mi < 4; ++mi)
#pragma unroll
    for (int ni = 0; ni < 4; ++ni) acc[mi][ni] = zero4;
#pragma unroll
  for (int kk = 0; kk < 4; ++kk) {
    bf16x8 af[4], bfr[4];
#pragma unroll
    for (int i = 0; i < 4; ++i) af[i] = *(const bf16x8*)(Anode + nbase[i] + kk * 32 + q * 8);
#pragma unroll
    for (int i = 0; i < 4; ++i) bfr[i] = *(const bf16x8*)(W1c + kk * 8192 + wofs[i]);
#pragma unroll
    for (int mi = 0; mi < 4; ++mi)
#pragma unroll
      for (int ni = 0; ni < 4; ++ni)
        acc[mi][ni] = __builtin_amdgcn_mfma_f32_16x16x32_bf16(af[mi], bfr[ni], acc[mi][ni], 0, 0, 0);
  }
  float b1v[4];
#pragma unroll
  for (int ni = 0; ni < 4; ++ni) {
    int ch = w * 64 + ni * 16 + ln;
    b1v[ni] = (ch < 128) ? b1[ch] : 0.f;
  }
#pragma unroll
  for (int mi = 0; mi < 4; ++mi)
#pragma unroll
    for (int r = 0; r < 4; ++r) {
      int node = tile * 64 + mi * 16 + q * 4 + r;
      if (node < NN) {
#pragma unroll
        for (int ni = 0; ni < 4; ++ni) {
          int ch = w * 64 + ni * 16 + ln;
          H1RC[(size_t)node * 256 + ch] = (short)f2bf(acc[mi][ni][r] + b1v[ni]);
        }
      }
    }
}

// ---------------- fused edge/coord MLP (edges presorted by row) ----------------
// h1 = silu(H1RC[row].lo + H1RC[col].hi + ea@W1ea)  -- per-node GEMM1 hoisted out.
// GEMM2/segment-sum in bf16. TRANSPOSED MFMA: D[chan][edge] (lane=edge).
template <int COORD>
__global__ __launch_bounds__(256, 4) void k_edge_gemm(
    const short* __restrict__ H1RC, const uint8_t* __restrict__ eaF8,
    const int* __restrict__ rowS, const int* __restrict__ colS,
    const uint8_t* __restrict__ W1f8, const short* __restrict__ W2l,
    const float* __restrict__ b2,
    const float* __restrict__ wred, const float* __restrict__ batt,
    const float* __restrict__ ndS, float* outAcc) {
  __shared__ __align__(16) short A2s[8192];  // h1^T 4x[64e][32c]; then M 2x[128c][32e]
  __shared__ float redp[64][2];
  __shared__ float redv[64];
  __shared__ int srow[64];
  __shared__ __align__(8) unsigned char srunS[64];
  __shared__ int runrowS[64];
  __shared__ int cntS[1];

  const int tid = threadIdx.x;
  const int lane = tid & 63;
  const int w = tid >> 6;
  const int ln = lane & 15, q = lane >> 4;
  const int wm = w >> 1, wn = w & 1;
  const int tile = blockIdx.x;

  if (tid < 64) srow[tid] = rowS[tile * 64 + tid];
  __syncthreads();

  // ---- segmented-run scan over sorted rows (wave 0 only) ----
  bool is_start = (tid < 64) && (tid == 0 || srow[tid] != srow[tid - 1]);
  unsigned long long bmask = __ballot(is_start);
  if (tid == 0) cntS[0] = __popcll(bmask);
  if (tid < 64) {
    int run = __popcll(bmask & ((1ull << lane) - 1ull)) + (is_start ? 1 : 0) - 1;
    srunS[tid] = (unsigned char)run;
    if (is_start) runrowS[run] = srow[tid];
  }
  // (published by epilogue1's barrier; read only after GEMM2)

  // per-lane sources
  const int e0 = wm * 32 + ln, e1 = e0 + 16;
  const size_t hr0 = (size_t)srow[e0] * 256, hr1 = (size_t)srow[e1] * 256;
  const size_t hc0 = (size_t)colS[tile * 64 + e0] * 256 + 128;
  const size_t hc1 = (size_t)colS[tile * 64 + e1] * 256 + 128;
  const size_t ea0 = (size_t)(tile * 64 + e0) * 16 + (q & 1) * 8;
  const size_t ea1 = (size_t)(tile * 64 + e1) * 16 + (q & 1) * 8;
  int wofs8[4], wofs[4];
#pragma unroll
  for (int i = 0; i < 4; ++i) {
    wofs8[i] = (wn * 64 + i * 16 + ln) * 32 + q * 8;      // fp8 bytes (ea block)
    wofs[i] = wfrag_off(wn * 64 + i * 16 + ln, q);        // bf16 shorts
  }

  // H1 gathers: per (ni, mi) 4 consecutive chans (q*4) of row/col halves (8B each)
  ushort4 xr[4][2], xc[4][2];
#pragma unroll
  for (int ni = 0; ni < 4; ++ni) {
    int cb = wn * 64 + ni * 16 + q * 4;
    xr[ni][0] = *(const ushort4*)(H1RC + hr0 + cb);
    xr[ni][1] = *(const ushort4*)(H1RC + hr1 + cb);
    xc[ni][0] = *(const ushort4*)(H1RC + hc0 + cb);
    xc[ni][1] = *(const ushort4*)(H1RC + hc1 + cb);
  }

  f32x4 acc[4][2];                           // [chan-tile ni][edge-tile mi]
  const f32x4 zero4 = {0.f, 0.f, 0.f, 0.f};
#pragma unroll
  for (int ni = 0; ni < 4; ++ni)
#pragma unroll
    for (int mi = 0; mi < 2; ++mi) acc[ni][mi] = zero4;

  // -------- ea-only fp8 MFMA step (K=32 covering the 9 ea dims) --------
  {
    const uint8_t* W1ea = W1f8 + 8 * 4096;
    f8frag wf[4], hf[2];
#pragma unroll
    for (int i = 0; i < 4; ++i) wf[i] = *(const f8frag*)(W1ea + wofs8[i]);
    hf[0] = (q < 2) ? *(const f8frag*)(eaF8 + ea0) : 0L;
    hf[1] = (q < 2) ? *(const f8frag*)(eaF8 + ea1) : 0L;
#pragma unroll
    for (int ni = 0; ni < 4; ++ni)
#pragma unroll
      for (int mi = 0; mi < 2; ++mi)
        acc[ni][mi] = __builtin_amdgcn_mfma_f32_16x16x32_fp8_fp8(wf[ni], hf[mi], acc[ni][mi], 0, 0, 0);
  }

  // -------- epilogue1: silu(ea + H1R[row] + H1C[col]) -> A2s bf16 [edge][chan] --------
#pragma unroll
  for (int ni = 0; ni < 4; ++ni) {
    int cb = wn * 64 + ni * 16 + q * 4;            // 4 consecutive chans per lane
    int kkb = cb >> 5, cc = (cb >> 3) & 3, j0 = cb & 7;
#pragma unroll
    for (int mi = 0; mi < 2; ++mi) {
      int edge = wm * 32 + mi * 16 + ln;
      int addr = kkb * 2048 + edge * 32 + ((cc ^ ((edge >> 1) & 3)) * 8) + j0;
      float h0 = silu_f(acc[ni][mi][0] + b2f(xr[ni][mi].x) + b2f(xc[ni][mi].x));
      float h1 = silu_f(acc[ni][mi][1] + b2f(xr[ni][mi].y) + b2f(xc[ni][mi].y));
      float h2 = silu_f(acc[ni][mi][2] + b2f(xr[ni][mi].z) + b2f(xc[ni][mi].z));
      float h3 = silu_f(acc[ni][mi][3] + b2f(xr[ni][mi].w) + b2f(xc[ni][mi].w));
      uint2 pk;
      pk.x = pack2bf(h0, h1);
      pk.y = pack2bf(h2, h3);
      *(uint2*)(A2s + addr) = pk;
    }
  }
  __syncthreads();

  // -------- GEMM2 (bf16): M^T[128c2 x 64e] = W2^T(A) x h1^T(B), barrier-free --------
  f32x4 acc2[4][2];
#pragma unroll
  for (int ni = 0; ni < 4; ++ni)
#pragma unroll
    for (int mi = 0; mi < 2; ++mi) acc2[ni][mi] = zero4;
#pragma unroll
  for (int kk = 0; kk < 4; ++kk) {
    bf16x8 wf[4], hf[2];
#pragma unroll
    for (int i = 0; i < 4; ++i) wf[i] = *(const bf16x8*)(W2l + kk * 4096 + wofs[i]);
#pragma unroll
    for (int i = 0; i < 2; ++i) hf[i] = frag_ld(A2s + kk * 2048, wm * 32 + i * 16 + ln, q);
#pragma unroll
    for (int ni = 0; ni < 4; ++ni)
#pragma unroll
      for (int mi = 0; mi < 2; ++mi)
        acc2[ni][mi] = __builtin_amdgcn_mfma_f32_16x16x32_bf16(wf[ni], hf[mi], acc2[ni][mi], 0, 0, 0);
  }

  // -------- epilogue2: silu + attention/phi dot (mostly in-lane) --------
  float4 b2v[4], wv[4];
#pragma unroll
  for (int ni = 0; ni < 4; ++ni) {
    b2v[ni] = *(const float4*)(b2 + wn * 64 + ni * 16 + q * 4);
    wv[ni]  = *(const float4*)(wred + wn * 64 + ni * 16 + q * 4);
  }
  float p[2] = {0.f, 0.f};
#pragma unroll
  for (int ni = 0; ni < 4; ++ni)
#pragma unroll
    for (int mi = 0; mi < 2; ++mi)
#pragma unroll
      for (int r = 0; r < 4; ++r) {
        float v = silu_f(acc2[ni][mi][r] + ((const float*)&b2v[ni])[r]);
        acc2[ni][mi][r] = v;
        p[mi] += v * ((const float*)&wv[ni])[r];
      }
#pragma unroll
  for (int mi = 0; mi < 2; ++mi) {
    p[mi] += __shfl_xor(p[mi], 16, 64);
    p[mi] += __shfl_xor(p[mi], 32, 64);
  }
  if (lane < 16) {
#pragma unroll
    for (int mi = 0; mi < 2; ++mi) redp[wm * 32 + mi * 16 + ln][wn] = p[mi];
  }
  __syncthreads();   // redp ready; all waves done with A2s (GEMM2)

  if (COORD == 0) {
    if (tid < 64) redv[tid] = sigm_f(redp[tid][0] + redp[tid][1] + batt[0]);
    __syncthreads();
    // M-tile 2x[128 chan][32 edge] swizzled blocks (B-operand layout for S-GEMM)
    float attv[2] = {redv[wm * 32 + ln], redv[wm * 32 + 16 + ln]};
#pragma unroll
    for (int ni = 0; ni < 4; ++ni)
#pragma unroll
      for (int mi = 0; mi < 2; ++mi) {
        int eb = mi * 16 + ln;
        int cE = (eb >> 3) & 3, jE = eb & 7;
#pragma unroll
        for (int r = 0; r < 4; ++r) {
          int chan2 = wn * 64 + ni * 16 + q * 4 + r;
          int addr = wm * 4096 + chan2 * 32 + ((cE ^ ((chan2 >> 1) & 3)) * 8) + jE;
          union { float f; uint32_t u; } vv;
          vv.f = acc2[ni][mi][r] * attv[mi];
          A2s[addr] = (short)((vv.u + 0x8000u) >> 16);   // round-half-up to bf16
        }
      }
    __syncthreads();
    // segment-sum via MFMA: agg[run][chan] = S[run][edge] @ M[edge][chan]
    const int nruns = cntS[0];
    bf16x8 bfrg[2][2];
#pragma unroll
    for (int kk = 0; kk < 2; ++kk)
#pragma unroll
      for (int ni = 0; ni < 2; ++ni)
        bfrg[kk][ni] = frag_ld(A2s + kk * 4096, w * 32 + ni * 16 + ln, q);
    const int npass = (nruns + 15) >> 4;
    for (int pp = 0; pp < npass; ++pp) {
      const unsigned int base = pp * 16;
      f32x4 a3c[2] = {zero4, zero4};
#pragma unroll
      for (int kk = 0; kk < 2; ++kk) {
        uint2 sb = *(const uint2*)(srunS + kk * 32 + q * 8);
        union { short s[8]; bf16x8 v; } af;
#pragma unroll
        for (int j = 0; j < 4; ++j)
          af.s[j] = (((sb.x >> (8 * j)) & 255u) == base + (unsigned)ln) ? (short)0x3F80 : (short)0;
#pragma unroll
        for (int j = 0; j < 4; ++j)
          af.s[4 + j] = (((sb.y >> (8 * j)) & 255u) == base + (unsigned)ln) ? (short)0x3F80 : (short)0;
        a3c[0] = __builtin_amdgcn_mfma_f32_16x16x32_bf16(af.v, bfrg[kk][0], a3c[0], 0, 0, 0);
        a3c[1] = __builtin_amdgcn_mfma_f32_16x16x32_bf16(af.v, bfrg[kk][1], a3c[1], 0, 0, 0);
      }
#pragma unroll
      for (int ni = 0; ni < 2; ++ni)
#pragma unroll
        for (int r = 0; r < 4; ++r) {
          int run = (int)base + q * 4 + r;
          if (run < nruns) {
            int rw = runrowS[run];
            atomicAdd(&outAcc[(size_t)rw * 128 + (w * 32 + ni * 16 + ln)], a3c[ni][r]);
          }
        }
    }
  } else {
    float* ndl = (float*)A2s;   // reuse: [64][3]
    if (tid < 64) {
      float phi = redp[tid][0] + redp[tid][1];
      ndl[tid * 3 + 0] = ndS[(size_t)(tile * 64 + tid) * 3 + 0] * phi;
      ndl[tid * 3 + 1] = ndS[(size_t)(tile * 64 + tid) * 3 + 1] * phi;
      ndl[tid * 3 + 2] = ndS[(size_t)(tile * 64 + tid) * 3 + 2] * phi;
    }
    __syncthreads();
    if (is_start) {   // run-start walkers (tid<64 implied)
      int myrow = srow[tid];
      float s0 = 0.f, s1 = 0.f, s2 = 0.f;
      for (int j = tid; j < 64 && srow[j] == myrow; ++j) {
        s0 += ndl[j * 3 + 0];
        s1 += ndl[j * 3 + 1];
        s2 += ndl[j * 3 + 2];
      }
      atomicAdd(&outAcc[myrow * 3 + 0], s0);
      atomicAdd(&outAcc[myrow * 3 + 1], s1);
      atomicAdd(&outAcc[myrow * 3 + 2], s2);
    }
  }
}

// ---------------- node MLP GEMM (residual update, 128-node tiles, bf16) ----------------
__global__ __launch_bounds__(256) void k_node_gemm(
    short* Anode, const short* __restrict__ Wn1l, const short* __restrict__ Wn2l,
    const float* __restrict__ b1, const float* __restrict__ b2,
    const float* __restrict__ xres, float* __restrict__ xout) {
  __shared__ short A2s[4 * 4096];

  const int tid = threadIdx.x;
  const int lane = tid & 63;
  const int w = tid >> 6;
  const int ln = lane & 15, q = lane >> 4;
  const int wm = w >> 1, wn = w & 1;
  const int tile = blockIdx.x;

  size_t nbase[4];
  int wofs[4];
#pragma unroll
  for (int i = 0; i < 4; ++i) {
    int node = tile * 128 + wm * 64 + i * 16 + ln;
    nbase[i] = (size_t)(node < NN ? node : (NN - 1)) * 256;
    wofs[i] = wfrag_off(wn * 64 + i * 16 + ln, q);
  }

  f32x4 acc[4][4];
  const f32x4 zero4 = {0.f, 0.f, 0.f, 0.f};
#pragma unroll
  for (int mi = 0; mi < 4; ++mi)
#pragma unroll
    for (int ni = 0; ni < 4; ++ni) acc[mi][ni] = zero4;

#pragma unroll
  for (int kk = 0; kk < 8; ++kk) {
    bf16x8 af[4], bfr[4];
#pragma unroll
    for (int i = 0; i < 4; ++i) af[i] = *(const bf16x8*)(Anode + nbase[i] + kk * 32 + q * 8);
#pragma unroll
    for (int i = 0; i < 4; ++i) bfr[i] = *(const bf16x8*)(Wn1l + kk * 4096 + wofs[i]);
#pragma unroll
    for (int mi = 0; mi < 4; ++mi)
#pragma unroll
      for (int ni = 0; ni < 4; ++ni)
        acc[mi][ni] = __builtin_amdgcn_mfma_f32_16x16x32_bf16(af[mi], bfr[ni], acc[mi][ni], 0, 0, 0);
  }

  float b1v[4];
#pragma unroll
  for (int ni = 0; ni < 4; ++ni) b1v[ni] = b1[wn * 64 + ni * 16 + ln];
#pragma unroll
  for (int mi = 0; mi < 4; ++mi)
#pragma unroll
    for (int ni = 0; ni < 4; ++ni) {
      int chan = wn * 64 + ni * 16 + ln;
      int kkb = chan >> 5, c = (chan >> 3) & 3, jj = chan & 7;
#pragma unroll
      for (int r = 0; r < 4; ++r) {
        int m = wm * 64 + mi * 16 + q * 4 + r;
        float v = silu_f(acc[mi][ni][r] + b1v[ni]);
        A2s[kkb * 4096 + m * 32 + ((c ^ ((m >> 1) & 3)) * 8) + jj] = (short)f2bf(v);
      }
    }
  __syncthreads();

  f32x4 acc2[4][4];
#pragma unroll
  for (int mi = 0; mi < 4; ++mi)
#pragma unroll
    for (int ni = 0; ni < 4; ++ni) acc2[mi][ni] = zero4;
#pragma unroll
  for (int kk = 0; kk < 4; ++kk) {
    bf16x8 af[4], bfr[4];
#pragma unroll
    for (int i = 0; i < 4; ++i) af[i] = frag_ld(A2s + kk * 4096, wm * 64 + i * 16 + ln, q);
#pragma unroll
    for (int i = 0; i < 4; ++i) bfr[i] = *(const bf16x8*)(Wn2l + kk * 4096 + wofs[i]);
#pragma unroll
    for (int mi = 0; mi < 4; ++mi)
#pragma unroll
      for (int ni = 0; ni < 4; ++ni)
        acc2[mi][ni] = __builtin_amdgcn_mfma_f32_16x16x32_bf16(af[mi], bfr[ni], acc2[mi][ni], 0, 0, 0);
  }

  float b2v[4];
#pragma unroll
  for (int ni = 0; ni < 4; ++ni) b2v[ni] = b2[wn * 64 + ni * 16 + ln];
#pragma unroll
  for (int mi = 0; mi < 4; ++mi)
#pragma unroll
    for (int r = 0; r < 4; ++r) {
      int m = wm * 64 + mi * 16 + q * 4 + r;
      int node = tile * 128 + m;
      if (node < NN) {
#pragma unroll
        for (int ni = 0; ni < 4; ++ni) {
          int chan = wn * 64 + ni * 16 + ln;
          float v = acc2[mi][ni][r] + b2v[ni] + xres[(size_t)node * 128 + chan];
          xout[(size_t)node * 128 + chan] = v;
          Anode[(size_t)node * 256 + chan] = (short)f2bf(v);
        }
      }
    }
}

extern "C" void kernel_launch(void* const* d_in, const int* in_sizes, int n_in,
                              void* d_out, int out_size, void* d_ws, size_t ws_size,
                              hipStream_t stream) {
  const float* x    = (const float*)d_in[0];
  const float* pos  = (const float*)d_in[1];
  const float* mask = (const float*)d_in[2];
  const float* eattr= (const float*)d_in[3];
  const int*   ei   = (const int*)d_in[4];
  const float* We1  = (const float*)d_in[5];
  const float* be1  = (const float*)d_in[6];
  const float* We2  = (const float*)d_in[7];
  const float* be2  = (const float*)d_in[8];
  const float* Watt = (const float*)d_in[9];
  const float* batt = (const float*)d_in[10];
  const float* Wn1  = (const float*)d_in[11];
  const float* bn1  = (const float*)d_in[12];
  const float* Wn2  = (const float*)d_in[13];
  const float* bn2  = (const float*)d_in[14];
  const float* cW1  = (const float*)d_in[15];
  const float* cb1  = (const float*)d_in[16];
  const float* cW2  = (const float*)d_in[17];
  const float* cb2  = (const float*)d_in[18];
  const float* cW3  = (const float*)d_in[19];

  char* p = (char*)d_ws;
  auto carve = [&](size_t bytes) { char* r = p; p += (bytes + 511) & ~(size_t)511; return r; };
  short*   Anode = (short*)carve((size_t)NN * 256 * 2);
  short*   H1RC  = (short*)carve((size_t)NN * 256 * 2);
  uint8_t* eaF8  = (uint8_t*)carve((size_t)NE * 16 + 256);
  int*     rowS  = (int*)carve((size_t)NE * 4);
  int*     colS  = (int*)carve((size_t)NE * 4);
  float*   ndS   = (float*)carve((size_t)NE * 3 * 4);
  float*   agg   = (float*)carve((size_t)NN * 128 * 4);
  float*   xcur  = (float*)carve((size_t)NN * 128 * 4);
  float*   pagg  = (float*)carve((size_t)NN * 3 * 4);
  uint8_t* W1f8  = (uint8_t*)carve(3 * 36864);
  short*   W2sw  = (short*)carve(3 * 16384 * 2);
  short*   Wn1sw = (short*)carve(2 * 32768 * 2);
  short*   Wn2sw = (short*)carve(2 * 16384 * 2);
  short*   W1csw = (short*)carve(3 * 32768 * 2);
  int*     cnt   = (int*)carve((size_t)NN * 4);
  int*     offs  = (int*)carve((size_t)NN * 4);
  int*     bsum  = (int*)carve(256 * 4);
  int*     inv   = (int*)carve((size_t)NE * 4);

  float* xout_f = (float*)d_out;        // N*128
  float* pout_f = xout_f + NN * 128;    // N*3

  k_prep_weights<<<1392, 256, 0, stream>>>(We1, We2, Wn1, Wn2, cW1, cW2,
                                           W1f8, W2sw, Wn1sw, Wn2sw, W1csw);
  k_x_prep<<<6250, 256, 0, stream>>>(x, Anode);

  // build row-sorted edge permutation (CSR order) -> inv[e] = sorted slot
  hipMemsetAsync(cnt, 0, (size_t)NN * 4, stream);
  k_hist<<<3125, 256, 0, stream>>>(ei, cnt);
  k_scan_block<<<196, 256, 0, stream>>>(cnt, offs, bsum);
  k_scan_top<<<1, 256, 0, stream>>>(bsum);
  k_scan_add<<<196, 256, 0, stream>>>(offs, bsum);
  k_scatter<<<3125, 256, 0, stream>>>(ei, offs, inv);
  k_edge_pre<<<3125, 256, 0, stream>>>(pos, eattr, ei, inv, rowS, colS, eaF8, ndS);

  for (int l = 0; l < 2; ++l) {
    k_h1<<<782, 256, 0, stream>>>(Anode, W1csw + l * 32768, be1 + l * 128, H1RC);
    hipMemsetAsync(agg, 0, (size_t)NN * 128 * 4, stream);
    k_edge_gemm<0><<<12500, 256, 0, stream>>>(H1RC, eaF8, rowS, colS,
        W1f8 + l * 36864, W2sw + l * 16384, be2 + l * 128,
        Watt + l * 128, batt + l, (const float*)nullptr, agg);
    k_nodeprep<<<25000, 256, 0, stream>>>(agg, Anode);
    k_node_gemm<<<391, 256, 0, stream>>>(Anode,
        Wn1sw + l * 32768, Wn2sw + l * 16384, bn1 + l * 128, bn2 + l * 128,
        l == 0 ? x : xcur, l == 0 ? xcur : xout_f);
  }
  k_h1<<<782, 256, 0, stream>>>(Anode, W1csw + 2 * 32768, cb1, H1RC);
  hipMemsetAsync(pagg, 0, (size_t)NN * 3 * 4, stream);
  k_edge_gemm<1><<<12500, 256, 0, stream>>>(H1RC, eaF8, rowS, colS,
      W1f8 + 2 * 36864, W2sw + 2 * 16384, cb2, cW3, (const float*)nullptr, ndS, pagg);
  k_pos_final<<<587, 256, 0, stream>>>(pos, mask, pagg, pout_f);
}

// Round 3
// 720.495 us; speedup vs baseline: 1.2341x; 1.1101x over previous
//
#include <hip/hip_runtime.h>
#include <hip/hip_bf16.h>
#include <stdint.h>

#define NN 50000
#define NE 800000
#define HH 128

typedef __bf16 bf16x8 __attribute__((ext_vector_type(8)));
typedef float  f32x4  __attribute__((ext_vector_type(4)));
typedef long   f8frag;   // 8 fp8 bytes = i64 MFMA operand

__device__ __forceinline__ unsigned short f2bf(float f) {
  union { float f; uint32_t u; } v; v.f = f;
  uint32_t r = v.u + 0x7FFFu + ((v.u >> 16) & 1u);
  return (unsigned short)(r >> 16);
}
__device__ __forceinline__ float b2f(unsigned short u) {
  union { float f; uint32_t u; } v; v.u = (uint32_t)u << 16; return v.f;
}
#if __has_builtin(__builtin_amdgcn_cvt_pk_bf16_f32)
typedef __bf16 bf16x2 __attribute__((ext_vector_type(2)));
__device__ __forceinline__ uint32_t pack2bf(float a, float b) {
  union { bf16x2 v; uint32_t u; } t;
  t.v = __builtin_amdgcn_cvt_pk_bf16_f32(a, b);
  return t.u;
}
#else
__device__ __forceinline__ uint32_t pack2bf(float a, float b) {
  return (uint32_t)f2bf(a) | ((uint32_t)f2bf(b) << 16);
}
#endif
__device__ __forceinline__ uint8_t f2fp8(float v) {
  return (uint8_t)(__builtin_amdgcn_cvt_pk_fp8_f32(v, 0.f, 0, false) & 0xff);
}
// fast silu/sigmoid
__device__ __forceinline__ float silu_f(float x) {
  return x * __builtin_amdgcn_rcpf(1.f + __expf(-x));
}
__device__ __forceinline__ float sigm_f(float x) {
  return __builtin_amdgcn_rcpf(1.f + __expf(-x));
}

// LDS tile blocks (bf16): [rows][32 k], 16B chunk c stored at c ^ ((row>>1)&3)
__device__ __forceinline__ bf16x8 frag_ld(const short* blk, int row, int q) {
  int c = q ^ ((row >> 1) & 3);
  return *(const bf16x8*)(blk + row * 32 + c * 8);
}
// bf16 global weight frag offset (swizzled prep layout, short-indexed)
__device__ __forceinline__ int wfrag_off(int row, int q) {
  return row * 32 + ((q ^ ((row >> 1) & 3)) * 8);
}

// ---------------- weight prep ----------------
// W1f8: 3 sets x [9 kk][128 n][32 k] fp8 (only kk=8 / ea block used by edge kernel)
// W2sw: 3 sets bf16 swizzled; Wn1sw/Wn2sw: 2 sets bf16 swizzled
// W1csw: 3 sets x [4 kk][256 n][32 k] bf16 swizzled (Wcat for per-node H1 GEMM)
__global__ void k_prep_weights(const float* We1, const float* We2, const float* Wn1,
                               const float* Wn2, const float* cW1, const float* cW2,
                               uint8_t* W1f8, short* W2sw, short* Wn1sw, short* Wn2sw,
                               short* W1csw) {
  int idx = blockIdx.x * 256 + threadIdx.x;
  if (idx < 110592) {                      // fp8 W1 (ks=265)
    int l = idx / 36864, rem = idx % 36864;
    const float* s = (l == 0) ? We1 : (l == 1) ? We1 + 33920 : cW1;
    int kkb = rem >> 12, r2 = rem & 4095;
    int n = r2 >> 5, kw = r2 & 31;
    int k = kkb * 32 + kw;
    float v = (k < 265) ? s[k * 128 + n] : 0.f;
    W1f8[idx] = f2fp8(v);
    return;
  }
  idx -= 110592;
  if (idx < 49152) {                       // bf16 W2, 3 sets, ks=128
    int l = idx >> 14, rem = idx & 16383;
    const float* s = (l == 0) ? We2 : (l == 1) ? We2 + 16384 : cW2;
    int kkb = rem >> 12, r2 = rem & 4095, n = r2 >> 5, kw = r2 & 31;
    int cp = kw >> 3, j = kw & 7, c = cp ^ ((n >> 1) & 3);
    int k = kkb * 32 + c * 8 + j;
    W2sw[(l << 14) + (rem)] = (short)f2bf(s[k * 128 + n]);
    return;
  }
  idx -= 49152;
  if (idx < 65536) {                       // bf16 Wn1, 2 sets, ks=256
    int l = idx >> 15, rem = idx & 32767;
    const float* s = Wn1 + l * 32768;
    int kkb = rem >> 12, r2 = rem & 4095, n = r2 >> 5, kw = r2 & 31;
    int cp = kw >> 3, j = kw & 7, c = cp ^ ((n >> 1) & 3);
    int k = kkb * 32 + c * 8 + j;
    Wn1sw[(l << 15) + rem] = (short)f2bf(s[k * 128 + n]);
    return;
  }
  idx -= 65536;
  if (idx < 32768) {                       // bf16 Wn2, 2 sets, ks=128
    int l = idx >> 14, rem = idx & 16383;
    const float* s = Wn2 + l * 16384;
    int kkb = rem >> 12, r2 = rem & 4095, n = r2 >> 5, kw = r2 & 31;
    int cp = kw >> 3, j = kw & 7, c = cp ^ ((n >> 1) & 3);
    int k = kkb * 32 + c * 8 + j;
    Wn2sw[(l << 14) + rem] = (short)f2bf(s[k * 128 + n]);
    return;
  }
  idx -= 32768;
  if (idx < 98304) {                       // bf16 W1cat, 3 sets, [4kk][256n][32k]
    int l = idx / 32768, rem = idx % 32768;
    const float* s = (l == 0) ? We1 : (l == 1) ? We1 + 33920 : cW1;
    int kkb = rem >> 13, r2 = rem & 8191, n = r2 >> 5, kw = r2 & 31;
    int cp = kw >> 3, j = kw & 7, c = cp ^ ((n >> 1) & 3);
    int k = kkb * 32 + c * 8 + j;          // 0..127
    float v = (n < 128) ? s[k * 128 + n] : s[(128 + k) * 128 + (n - 128)];
    W1csw[l * 32768 + rem] = (short)f2bf(v);
  }
}

// ---------------- small prep kernels ----------------
// x (f32) -> Anode bf16 [node][128]
__global__ void k_x_prep(const float* __restrict__ x, short* __restrict__ Anode) {
  int i = blockIdx.x * 256 + threadIdx.x;     // float4 index
  if (i < NN * 32) {
    float4 v = ((const float4*)x)[i];
    ushort4 pk;
    pk.x = f2bf(v.x); pk.y = f2bf(v.y); pk.z = f2bf(v.z); pk.w = f2bf(v.w);
    *(ushort4*)(Anode + i * 4) = pk;
  }
}
// after sort: original-order streaming reads, scatter-writes into sorted slots
__global__ void k_edge_pre(const float* __restrict__ pos, const float* __restrict__ eattr,
                           const int* __restrict__ ei, const int* __restrict__ inv,
                           int* __restrict__ rowS, int* __restrict__ colS,
                           uint8_t* __restrict__ eaF8, float* __restrict__ ndS) {
  int e = blockIdx.x * 256 + threadIdx.x;
  if (e >= NE) return;
  int r = ei[e], c = ei[NE + e];
  float dx = pos[r * 3 + 0] - pos[c * 3 + 0];
  float dy = pos[r * 3 + 1] - pos[c * 3 + 1];
  float dz = pos[r * 3 + 2] - pos[c * 3 + 2];
  float d2 = dx * dx + dy * dy + dz * dz;
  float invd = __builtin_amdgcn_rcpf(sqrtf(d2) + 1.f);   // NC = 1.0
  int p = inv[e];
  rowS[p] = r;
  colS[p] = c;
  ndS[p * 3 + 0] = dx * invd;
  ndS[p * 3 + 1] = dy * invd;
  ndS[p * 3 + 2] = dz * invd;
  const float* ea = eattr + (size_t)e * 8;
  uint32_t w0 = __builtin_amdgcn_cvt_pk_fp8_f32(d2, ea[0], 0, false);
  w0 = __builtin_amdgcn_cvt_pk_fp8_f32(ea[1], ea[2], w0, true);
  uint32_t w1 = __builtin_amdgcn_cvt_pk_fp8_f32(ea[3], ea[4], 0, false);
  w1 = __builtin_amdgcn_cvt_pk_fp8_f32(ea[5], ea[6], w1, true);
  uint32_t w2 = __builtin_amdgcn_cvt_pk_fp8_f32(ea[7], 0.f, 0, false);
  uint4 v = {w0, w1, w2, 0u};
  *(uint4*)(eaF8 + (size_t)p * 16) = v;
}
__global__ void k_pos_final(const float* __restrict__ pos, const float* __restrict__ mask,
                            const float* __restrict__ pagg, float* __restrict__ out) {
  int i = blockIdx.x * 256 + threadIdx.x;
  if (i < NN * 3) out[i] = pos[i] + pagg[i] * 0.01f * mask[i / 3];
}

// ---------------- CSR sort of edges by destination row ----------------
__global__ void k_hist(const int* __restrict__ ei, int* __restrict__ cnt) {
  int e = blockIdx.x * 256 + threadIdx.x;
  if (e < NE) atomicAdd(&cnt[ei[e]], 1);
}
__global__ void k_scan_block(const int* __restrict__ cnt, int* __restrict__ offs,
                             int* __restrict__ bsum) {
  __shared__ int s[256];
  int i = blockIdx.x * 256 + threadIdx.x;
  int v = (i < NN) ? cnt[i] : 0;
  s[threadIdx.x] = v;
  __syncthreads();
#pragma unroll
  for (int d = 1; d < 256; d <<= 1) {
    int t = (threadIdx.x >= d) ? s[threadIdx.x - d] : 0;
    __syncthreads();
    s[threadIdx.x] += t;
    __syncthreads();
  }
  if (i < NN) offs[i] = s[threadIdx.x] - v;
  if (threadIdx.x == 255) bsum[blockIdx.x] = s[255];
}
__global__ void k_scan_top(int* __restrict__ bsum) {
  __shared__ int s[256];
  int v = (threadIdx.x < 196) ? bsum[threadIdx.x] : 0;
  s[threadIdx.x] = v;
  __syncthreads();
#pragma unroll
  for (int d = 1; d < 256; d <<= 1) {
    int t = (threadIdx.x >= d) ? s[threadIdx.x - d] : 0;
    __syncthreads();
    s[threadIdx.x] += t;
    __syncthreads();
  }
  if (threadIdx.x < 196) bsum[threadIdx.x] = s[threadIdx.x] - v;
}
__global__ void k_scan_add(int* __restrict__ offs, const int* __restrict__ bsum) {
  int i = blockIdx.x * 256 + threadIdx.x;
  if (i < NN) offs[i] += bsum[blockIdx.x];
}
__global__ void k_scatter(const int* __restrict__ ei, int* __restrict__ offs,
                          int* __restrict__ inv) {
  int e = blockIdx.x * 256 + threadIdx.x;
  if (e < NE) inv[e] = atomicAdd(&offs[ei[e]], 1);
}

// ---------------- per-node H1 precompute: H1RC[node][256] = x @ W1cat (+b1 on low half) --
// 64 nodes/block, 4 waves; wave w owns 64 output chans (w*64..+63).
// Store PERMUTED within each 128-half: logical c = wn*64+ni*16+q*4+r stored at
// p = wn*64 + q*16 + ni*4 + r  -> edge kernel reads 16 contiguous shorts per (wn,q).
__global__ __launch_bounds__(256) void k_h1(
    const short* __restrict__ Anode, const short* __restrict__ W1c,
    const float* __restrict__ b1, short* __restrict__ H1RC) {
  const int tid = threadIdx.x, lane = tid & 63, w = tid >> 6;
  const int ln = lane & 15, q = lane >> 4;
  const int tile = blockIdx.x;
  size_t nbase[4];
  int wofs[4];
#pragma unroll
  for (int i = 0; i < 4; ++i) {
    int node = tile * 64 + i * 16 + ln;
    nbase[i] = (size_t)(node < NN ? node : (NN - 1)) * 128;
    int row = w * 64 + i * 16 + ln;
    wofs[i] = row * 32 + ((q ^ ((row >> 1) & 3)) * 8);
  }
  f32x4 acc[4][4];
  const f32x4 zero4 = {0.f, 0.f, 0.f, 0.f};
#pragma unroll
  for (int mi = 0; mi < 4; ++mi)
#pragma unroll
    for (int ni = 0; ni < 4; ++ni) acc[mi][ni] = zero4;
#pragma unroll
  for (int kk = 0; kk < 4; ++kk) {
    bf16x8 af[4], bfr[4];
#pragma unroll
    for (int i = 0; i < 4; ++i) af[i] = *(const bf16x8*)(Anode + nbase[i] + kk * 32 + q * 8);
#pragma unroll
    for (int i = 0; i < 4; ++i) bfr[i] = *(const bf16x8*)(W1c + kk * 8192 + wofs[i]);
#pragma unroll
    for (int mi = 0; mi < 4; ++mi)
#pragma unroll
      for (int ni = 0; ni < 4; ++ni)
        acc[mi][ni] = __builtin_amdgcn_mfma_f32_16x16x32_bf16(af[mi], bfr[ni], acc[mi][ni], 0, 0, 0);
  }
  float b1v[4];
#pragma unroll
  for (int ni = 0; ni < 4; ++ni) {
    int ch = w * 64 + ni * 16 + ln;
    b1v[ni] = (ch < 128) ? b1[ch] : 0.f;
  }
#pragma unroll
  for (int mi = 0; mi < 4; ++mi)
#pragma unroll
    for (int r = 0; r < 4; ++r) {
      int node = tile * 64 + mi * 16 + q * 4 + r;
      if (node < NN) {
#pragma unroll
        for (int ni = 0; ni < 4; ++ni) {
          int ph = (w >> 1) * 128 + (w & 1) * 64 + ((ln >> 2) << 4) + (ni << 2) + (ln & 3);
          H1RC[(size_t)node * 256 + ph] = (short)f2bf(acc[mi][ni][r] + b1v[ni]);
        }
      }
    }
}

// ---------------- fused edge/coord MLP (edges presorted by row) ----------------
// h1 = silu(H1RC[row].lo + H1RC[col].hi + ea@W1ea)  -- per-node GEMM1 hoisted out.
// GEMM2/segment-sum in bf16. TRANSPOSED MFMA: D[chan][edge] (lane=edge).
// Attention is folded into the segment-sum S matrix (S entries = bf16 sigma(att)).
template <int COORD>
__global__ __launch_bounds__(256, 4) void k_edge_gemm(
    const short* __restrict__ H1RC, const uint8_t* __restrict__ eaF8,
    const int* __restrict__ rowS, const int* __restrict__ colS,
    const uint8_t* __restrict__ W1f8, const short* __restrict__ W2l,
    const float* __restrict__ b2,
    const float* __restrict__ wred, const float* __restrict__ batt,
    const float* __restrict__ ndS, float* outAcc) {
  __shared__ __align__(16) short A2s[8192];  // h1^T 4x[64e][32c]; then M 2x[128c][32e]
  __shared__ float redp[64][2];
  __shared__ __align__(16) unsigned short attb[64];
  __shared__ int srow[64];
  __shared__ __align__(8) unsigned char srunS[64];
  __shared__ int runrowS[64];
  __shared__ int cntS[1];

  const int tid = threadIdx.x;
  const int lane = tid & 63;
  const int w = tid >> 6;
  const int ln = lane & 15, q = lane >> 4;
  const int wm = w >> 1, wn = w & 1;
  const int tile = blockIdx.x;

  if (tid < 64) srow[tid] = rowS[tile * 64 + tid];
  __syncthreads();

  // ---- segmented-run scan over sorted rows (wave 0 only) ----
  bool is_start = (tid < 64) && (tid == 0 || srow[tid] != srow[tid - 1]);
  unsigned long long bmask = __ballot(is_start);
  if (tid == 0) cntS[0] = __popcll(bmask);
  if (tid < 64) {
    int run = __popcll(bmask & ((1ull << lane) - 1ull)) + (is_start ? 1 : 0) - 1;
    srunS[tid] = (unsigned char)run;
    if (is_start) runrowS[run] = srow[tid];
  }
  // (published by epilogue1's barrier; read only after GEMM2)

  // per-lane sources (uint32 offsets -> saddr-form loads)
  const int e0 = wm * 32 + ln, e1 = e0 + 16;
  const uint32_t cbp = (uint32_t)(wn * 64 + q * 16);   // permuted chan-group base
  const uint32_t hr0 = (uint32_t)srow[e0] * 256u + cbp;
  const uint32_t hr1 = (uint32_t)srow[e1] * 256u + cbp;
  const uint32_t hc0 = (uint32_t)colS[tile * 64 + e0] * 256u + 128u + cbp;
  const uint32_t hc1 = (uint32_t)colS[tile * 64 + e1] * 256u + 128u + cbp;
  const uint32_t ea0 = (uint32_t)(tile * 64 + e0) * 16u + (uint32_t)((q & 1) * 8);
  const uint32_t ea1 = (uint32_t)(tile * 64 + e1) * 16u + (uint32_t)((q & 1) * 8);
  int wofs8[4], wofs[4];
#pragma unroll
  for (int i = 0; i < 4; ++i) {
    wofs8[i] = (wn * 64 + i * 16 + ln) * 32 + q * 8;      // fp8 bytes (ea block)
    wofs[i] = wfrag_off(wn * 64 + i * 16 + ln, q);        // bf16 shorts
  }

  // H1 gathers: 16B each; [mi edge][half] halves cover ni{0,1} / ni{2,3}
  union U8 { uint4 v; unsigned short s[8]; };
  U8 xr[2][2], xc[2][2];
  xr[0][0].v = *(const uint4*)(H1RC + hr0);
  xr[0][1].v = *(const uint4*)(H1RC + hr0 + 8);
  xr[1][0].v = *(const uint4*)(H1RC + hr1);
  xr[1][1].v = *(const uint4*)(H1RC + hr1 + 8);
  xc[0][0].v = *(const uint4*)(H1RC + hc0);
  xc[0][1].v = *(const uint4*)(H1RC + hc0 + 8);
  xc[1][0].v = *(const uint4*)(H1RC + hc1);
  xc[1][1].v = *(const uint4*)(H1RC + hc1 + 8);

  f32x4 acc[4][2];                           // [chan-tile ni][edge-tile mi]
  const f32x4 zero4 = {0.f, 0.f, 0.f, 0.f};
#pragma unroll
  for (int ni = 0; ni < 4; ++ni)
#pragma unroll
    for (int mi = 0; mi < 2; ++mi) acc[ni][mi] = zero4;

  // -------- ea-only fp8 MFMA step (K=32 covering the 9 ea dims) --------
  {
    const uint8_t* W1ea = W1f8 + 8 * 4096;
    f8frag wf[4], hf[2];
#pragma unroll
    for (int i = 0; i < 4; ++i) wf[i] = *(const f8frag*)(W1ea + wofs8[i]);
    hf[0] = (q < 2) ? *(const f8frag*)(eaF8 + ea0) : 0L;
    hf[1] = (q < 2) ? *(const f8frag*)(eaF8 + ea1) : 0L;
#pragma unroll
    for (int ni = 0; ni < 4; ++ni)
#pragma unroll
      for (int mi = 0; mi < 2; ++mi)
        acc[ni][mi] = __builtin_amdgcn_mfma_f32_16x16x32_fp8_fp8(wf[ni], hf[mi], acc[ni][mi], 0, 0, 0);
  }

  // -------- epilogue1: silu(ea + H1R[row] + H1C[col]) -> A2s bf16 [edge][chan] --------
#pragma unroll
  for (int ni = 0; ni < 4; ++ni) {
    int cb = wn * 64 + ni * 16 + q * 4;            // 4 consecutive logical chans
    int kkb = cb >> 5, cc = (cb >> 3) & 3, j0 = cb & 7;
    const int hh = ni >> 1, b4 = (ni & 1) * 4;
#pragma unroll
    for (int mi = 0; mi < 2; ++mi) {
      int edge = wm * 32 + mi * 16 + ln;
      int addr = kkb * 2048 + edge * 32 + ((cc ^ ((edge >> 1) & 3)) * 8) + j0;
      float h0 = silu_f(acc[ni][mi][0] + b2f(xr[mi][hh].s[b4 + 0]) + b2f(xc[mi][hh].s[b4 + 0]));
      float h1 = silu_f(acc[ni][mi][1] + b2f(xr[mi][hh].s[b4 + 1]) + b2f(xc[mi][hh].s[b4 + 1]));
      float h2 = silu_f(acc[ni][mi][2] + b2f(xr[mi][hh].s[b4 + 2]) + b2f(xc[mi][hh].s[b4 + 2]));
      float h3 = silu_f(acc[ni][mi][3] + b2f(xr[mi][hh].s[b4 + 3]) + b2f(xc[mi][hh].s[b4 + 3]));
      uint2 pk;
      pk.x = pack2bf(h0, h1);
      pk.y = pack2bf(h2, h3);
      *(uint2*)(A2s + addr) = pk;
    }
  }
  __syncthreads();

  // -------- GEMM2 (bf16): M^T[128c2 x 64e] = W2^T(A) x h1^T(B), barrier-free --------
  f32x4 acc2[4][2];
#pragma unroll
  for (int ni = 0; ni < 4; ++ni)
#pragma unroll
    for (int mi = 0; mi < 2; ++mi) acc2[ni][mi] = zero4;
#pragma unroll
  for (int kk = 0; kk < 4; ++kk) {
    bf16x8 wf[4], hf[2];
#pragma unroll
    for (int i = 0; i < 4; ++i) wf[i] = *(const bf16x8*)(W2l + kk * 4096 + wofs[i]);
#pragma unroll
    for (int i = 0; i < 2; ++i) hf[i] = frag_ld(A2s + kk * 2048, wm * 32 + i * 16 + ln, q);
#pragma unroll
    for (int ni = 0; ni < 4; ++ni)
#pragma unroll
      for (int mi = 0; mi < 2; ++mi)
        acc2[ni][mi] = __builtin_amdgcn_mfma_f32_16x16x32_bf16(wf[ni], hf[mi], acc2[ni][mi], 0, 0, 0);
  }

  // -------- epilogue2: silu + attention/phi dot (mostly in-lane) --------
  float4 b2v[4], wv[4];
#pragma unroll
  for (int ni = 0; ni < 4; ++ni) {
    b2v[ni] = *(const float4*)(b2 + wn * 64 + ni * 16 + q * 4);
    wv[ni]  = *(const float4*)(wred + wn * 64 + ni * 16 + q * 4);
  }
  float p[2] = {0.f, 0.f};
#pragma unroll
  for (int ni = 0; ni < 4; ++ni)
#pragma unroll
    for (int mi = 0; mi < 2; ++mi)
#pragma unroll
      for (int r = 0; r < 4; ++r) {
        float v = silu_f(acc2[ni][mi][r] + ((const float*)&b2v[ni])[r]);
        acc2[ni][mi][r] = v;
        p[mi] += v * ((const float*)&wv[ni])[r];
      }
#pragma unroll
  for (int mi = 0; mi < 2; ++mi) {
    p[mi] += __shfl_xor(p[mi], 16, 64);
    p[mi] += __shfl_xor(p[mi], 32, 64);
  }
  if (lane < 16) {
#pragma unroll
    for (int mi = 0; mi < 2; ++mi) redp[wm * 32 + mi * 16 + ln][wn] = p[mi];
  }
  __syncthreads();   // redp ready; all waves done with A2s (GEMM2)

  if (COORD == 0) {
    if (tid < 64) attb[tid] = f2bf(sigm_f(redp[tid][0] + redp[tid][1] + batt[0]));
    // M-tile 2x[128 chan][32 edge] swizzled blocks (B-operand layout for S-GEMM),
    // UNscaled -- attention rides in the S matrix.
#pragma unroll
    for (int ni = 0; ni < 4; ++ni)
#pragma unroll
      for (int mi = 0; mi < 2; ++mi) {
        int eb = mi * 16 + ln;
        int cE = (eb >> 3) & 3, jE = eb & 7;
#pragma unroll
        for (int r = 0; r < 4; ++r) {
          int chan2 = wn * 64 + ni * 16 + q * 4 + r;
          int addr = wm * 4096 + chan2 * 32 + ((cE ^ ((chan2 >> 1) & 3)) * 8) + jE;
          union { float f; uint32_t u; } vv;
          vv.f = acc2[ni][mi][r];
          A2s[addr] = (short)((vv.u + 0x8000u) >> 16);   // round-half-up to bf16
        }
      }
    __syncthreads();   // attb + M ready
    // segment-sum via MFMA: agg[run][chan] = S[run][edge] @ M[edge][chan]
    const int nruns = cntS[0];
    bf16x8 bfrg[2][2];
#pragma unroll
    for (int kk = 0; kk < 2; ++kk)
#pragma unroll
      for (int ni = 0; ni < 2; ++ni)
        bfrg[kk][ni] = frag_ld(A2s + kk * 4096, w * 32 + ni * 16 + ln, q);
    const int npass = (nruns + 15) >> 4;
    for (int pp = 0; pp < npass; ++pp) {
      const unsigned int base = pp * 16;
      f32x4 a3c[2] = {zero4, zero4};
#pragma unroll
      for (int kk = 0; kk < 2; ++kk) {
        uint2 sb = *(const uint2*)(srunS + kk * 32 + q * 8);
        U8 ab;
        ab.v = *(const uint4*)(attb + kk * 32 + q * 8);
        union { short s[8]; bf16x8 v; } af;
#pragma unroll
        for (int j = 0; j < 4; ++j)
          af.s[j] = (((sb.x >> (8 * j)) & 255u) == base + (unsigned)ln) ? (short)ab.s[j] : (short)0;
#pragma unroll
        for (int j = 0; j < 4; ++j)
          af.s[4 + j] = (((sb.y >> (8 * j)) & 255u) == base + (unsigned)ln) ? (short)ab.s[4 + j] : (short)0;
        a3c[0] = __builtin_amdgcn_mfma_f32_16x16x32_bf16(af.v, bfrg[kk][0], a3c[0], 0, 0, 0);
        a3c[1] = __builtin_amdgcn_mfma_f32_16x16x32_bf16(af.v, bfrg[kk][1], a3c[1], 0, 0, 0);
      }
#pragma unroll
      for (int ni = 0; ni < 2; ++ni)
#pragma unroll
        for (int r = 0; r < 4; ++r) {
          int run = (int)base + q * 4 + r;
          if (run < nruns) {
            int rw = runrowS[run];
            atomicAdd(&outAcc[(size_t)rw * 128 + (w * 32 + ni * 16 + ln)], a3c[ni][r]);
          }
        }
    }
  } else {
    float* ndl = (float*)A2s;   // reuse: [64][3]
    if (tid < 64) {
      float phi = redp[tid][0] + redp[tid][1];
      ndl[tid * 3 + 0] = ndS[(size_t)(tile * 64 + tid) * 3 + 0] * phi;
      ndl[tid * 3 + 1] = ndS[(size_t)(tile * 64 + tid) * 3 + 1] * phi;
      ndl[tid * 3 + 2] = ndS[(size_t)(tile * 64 + tid) * 3 + 2] * phi;
    }
    __syncthreads();
    if (is_start) {   // run-start walkers (tid<64 implied)
      int myrow = srow[tid];
      float s0 = 0.f, s1 = 0.f, s2 = 0.f;
      for (int j = tid; j < 64 && srow[j] == myrow; ++j) {
        s0 += ndl[j * 3 + 0];
        s1 += ndl[j * 3 + 1];
        s2 += ndl[j * 3 + 2];
      }
      atomicAdd(&outAcc[myrow * 3 + 0], s0);
      atomicAdd(&outAcc[myrow * 3 + 1], s1);
      atomicAdd(&outAcc[myrow * 3 + 2], s2);
    }
  }
}

// ---------------- node MLP GEMM (residual update, 64-node tiles, bf16) ----------------
// K-upper half (agg part) read directly from agg f32 with 0.01 scale fused
// (replaces the separate k_nodeprep dispatch).
__global__ __launch_bounds__(256) void k_node_gemm(
    short* Anode, const float* __restrict__ agg,
    const short* __restrict__ Wn1l, const short* __restrict__ Wn2l,
    const float* __restrict__ b1, const float* __restrict__ b2,
    const float* __restrict__ xres, float* __restrict__ xout) {
  __shared__ short A2s[4 * 2048];   // h1 staging [4kk][64 m][32 k]

  const int tid = threadIdx.x;
  const int lane = tid & 63;
  const int w = tid >> 6;
  const int ln = lane & 15, q = lane >> 4;
  const int wm = w >> 1, wn = w & 1;
  const int tile = blockIdx.x;

  int nidx[2];
  size_t nbase[2];
  int wofs[4];
#pragma unroll
  for (int i = 0; i < 2; ++i) {
    int node = tile * 64 + wm * 32 + i * 16 + ln;
    nidx[i] = node < NN ? node : (NN - 1);
    nbase[i] = (size_t)nidx[i] * 128;
  }
#pragma unroll
  for (int i = 0; i < 4; ++i) wofs[i] = wfrag_off(wn * 64 + i * 16 + ln, q);

  f32x4 acc[2][4];
  const f32x4 zero4 = {0.f, 0.f, 0.f, 0.f};
#pragma unroll
  for (int mi = 0; mi < 2; ++mi)
#pragma unroll
    for (int ni = 0; ni < 4; ++ni) acc[mi][ni] = zero4;

#pragma unroll
  for (int kk = 0; kk < 8; ++kk) {
    bf16x8 af[2], bfr[4];
#pragma unroll
    for (int i = 0; i < 2; ++i) {
      if (kk < 4) {
        af[i] = *(const bf16x8*)(Anode + nbase[i] + kk * 32 + q * 8);
      } else {
        const float* ag = agg + nbase[i] + (kk - 4) * 32 + q * 8;
        float4 lo = *(const float4*)ag;
        float4 hi = *(const float4*)(ag + 4);
        union { uint32_t u[4]; bf16x8 v; } t;
        t.u[0] = pack2bf(lo.x * 0.01f, lo.y * 0.01f);
        t.u[1] = pack2bf(lo.z * 0.01f, lo.w * 0.01f);
        t.u[2] = pack2bf(hi.x * 0.01f, hi.y * 0.01f);
        t.u[3] = pack2bf(hi.z * 0.01f, hi.w * 0.01f);
        af[i] = t.v;
      }
    }
#pragma unroll
    for (int i = 0; i < 4; ++i) bfr[i] = *(const bf16x8*)(Wn1l + kk * 4096 + wofs[i]);
#pragma unroll
    for (int mi = 0; mi < 2; ++mi)
#pragma unroll
      for (int ni = 0; ni < 4; ++ni)
        acc[mi][ni] = __builtin_amdgcn_mfma_f32_16x16x32_bf16(af[mi], bfr[ni], acc[mi][ni], 0, 0, 0);
  }

  float b1v[4];
#pragma unroll
  for (int ni = 0; ni < 4; ++ni) b1v[ni] = b1[wn * 64 + ni * 16 + ln];
#pragma unroll
  for (int mi = 0; mi < 2; ++mi)
#pragma unroll
    for (int ni = 0; ni < 4; ++ni) {
      int chan = wn * 64 + ni * 16 + ln;
      int kkb = chan >> 5, c = (chan >> 3) & 3, jj = chan & 7;
#pragma unroll
      for (int r = 0; r < 4; ++r) {
        int m = wm * 32 + mi * 16 + q * 4 + r;
        float v = silu_f(acc[mi][ni][r] + b1v[ni]);
        A2s[kkb * 2048 + m * 32 + ((c ^ ((m >> 1) & 3)) * 8) + jj] = (short)f2bf(v);
      }
    }
  __syncthreads();

  f32x4 acc2[2][4];
#pragma unroll
  for (int mi = 0; mi < 2; ++mi)
#pragma unroll
    for (int ni = 0; ni < 4; ++ni) acc2[mi][ni] = zero4;
#pragma unroll
  for (int kk = 0; kk < 4; ++kk) {
    bf16x8 af[2], bfr[4];
#pragma unroll
    for (int i = 0; i < 2; ++i) af[i] = frag_ld(A2s + kk * 2048, wm * 32 + i * 16 + ln, q);
#pragma unroll
    for (int i = 0; i < 4; ++i) bfr[i] = *(const bf16x8*)(Wn2l + kk * 4096 + wofs[i]);
#pragma unroll
    for (int mi = 0; mi < 2; ++mi)
#pragma unroll
      for (int ni = 0; ni < 4; ++ni)
        acc2[mi][ni] = __builtin_amdgcn_mfma_f32_16x16x32_bf16(af[mi], bfr[ni], acc2[mi][ni], 0, 0, 0);
  }

  float b2v[4];
#pragma unroll
  for (int ni = 0; ni < 4; ++ni) b2v[ni] = b2[wn * 64 + ni * 16 + ln];
#pragma unroll
  for (int mi = 0; mi < 2; ++mi)
#pragma unroll
    for (int r = 0; r < 4; ++r) {
      int m = wm * 32 + mi * 16 + q * 4 + r;
      int node = tile * 64 + m;
      if (node < NN) {
#pragma unroll
        for (int ni = 0; ni < 4; ++ni) {
          int chan = wn * 64 + ni * 16 + ln;
          float v = acc2[mi][ni][r] + b2v[ni] + xres[(size_t)node * 128 + chan];
          xout[(size_t)node * 128 + chan] = v;
          Anode[(size_t)node * 128 + chan] = (short)f2bf(v);
        }
      }
    }
}

extern "C" void kernel_launch(void* const* d_in, const int* in_sizes, int n_in,
                              void* d_out, int out_size, void* d_ws, size_t ws_size,
                              hipStream_t stream) {
  const float* x    = (const float*)d_in[0];
  const float* pos  = (const float*)d_in[1];
  const float* mask = (const float*)d_in[2];
  const float* eattr= (const float*)d_in[3];
  const int*   ei   = (const int*)d_in[4];
  const float* We1  = (const float*)d_in[5];
  const float* be1  = (const float*)d_in[6];
  const float* We2  = (const float*)d_in[7];
  const float* be2  = (const float*)d_in[8];
  const float* Watt = (const float*)d_in[9];
  const float* batt = (const float*)d_in[10];
  const float* Wn1  = (const float*)d_in[11];
  const float* bn1  = (const float*)d_in[12];
  const float* Wn2  = (const float*)d_in[13];
  const float* bn2  = (const float*)d_in[14];
  const float* cW1  = (const float*)d_in[15];
  const float* cb1  = (const float*)d_in[16];
  const float* cW2  = (const float*)d_in[17];
  const float* cb2  = (const float*)d_in[18];
  const float* cW3  = (const float*)d_in[19];

  char* p = (char*)d_ws;
  auto carve = [&](size_t bytes) { char* r = p; p += (bytes + 511) & ~(size_t)511; return r; };
  short*   Anode = (short*)carve((size_t)NN * 128 * 2);
  short*   H1RC  = (short*)carve((size_t)NN * 256 * 2);
  uint8_t* eaF8  = (uint8_t*)carve((size_t)NE * 16 + 256);
  int*     rowS  = (int*)carve((size_t)NE * 4);
  int*     colS  = (int*)carve((size_t)NE * 4);
  float*   ndS   = (float*)carve((size_t)NE * 3 * 4);
  float*   agg   = (float*)carve((size_t)NN * 128 * 4);
  float*   xcur  = (float*)carve((size_t)NN * 128 * 4);
  float*   pagg  = (float*)carve((size_t)NN * 3 * 4);
  uint8_t* W1f8  = (uint8_t*)carve(3 * 36864);
  short*   W2sw  = (short*)carve(3 * 16384 * 2);
  short*   Wn1sw = (short*)carve(2 * 32768 * 2);
  short*   Wn2sw = (short*)carve(2 * 16384 * 2);
  short*   W1csw = (short*)carve(3 * 32768 * 2);
  int*     cnt   = (int*)carve((size_t)NN * 4);
  int*     offs  = (int*)carve((size_t)NN * 4);
  int*     bsum  = (int*)carve(256 * 4);
  int*     inv   = (int*)carve((size_t)NE * 4);

  float* xout_f = (float*)d_out;        // N*128
  float* pout_f = xout_f + NN * 128;    // N*3

  k_prep_weights<<<1392, 256, 0, stream>>>(We1, We2, Wn1, Wn2, cW1, cW2,
                                           W1f8, W2sw, Wn1sw, Wn2sw, W1csw);
  k_x_prep<<<6250, 256, 0, stream>>>(x, Anode);

  // build row-sorted edge permutation (CSR order) -> inv[e] = sorted slot
  hipMemsetAsync(cnt, 0, (size_t)NN * 4, stream);
  k_hist<<<3125, 256, 0, stream>>>(ei, cnt);
  k_scan_block<<<196, 256, 0, stream>>>(cnt, offs, bsum);
  k_scan_top<<<1, 256, 0, stream>>>(bsum);
  k_scan_add<<<196, 256, 0, stream>>>(offs, bsum);
  k_scatter<<<3125, 256, 0, stream>>>(ei, offs, inv);
  k_edge_pre<<<3125, 256, 0, stream>>>(pos, eattr, ei, inv, rowS, colS, eaF8, ndS);

  for (int l = 0; l < 2; ++l) {
    k_h1<<<782, 256, 0, stream>>>(Anode, W1csw + l * 32768, be1 + l * 128, H1RC);
    hipMemsetAsync(agg, 0, (size_t)NN * 128 * 4, stream);
    k_edge_gemm<0><<<12500, 256, 0, stream>>>(H1RC, eaF8, rowS, colS,
        W1f8 + l * 36864, W2sw + l * 16384, be2 + l * 128,
        Watt + l * 128, batt + l, (const float*)nullptr, agg);
    k_node_gemm<<<782, 256, 0, stream>>>(Anode, agg,
        Wn1sw + l * 32768, Wn2sw + l * 16384, bn1 + l * 128, bn2 + l * 128,
        l == 0 ? x : xcur, l == 0 ? xcur : xout_f);
  }
  k_h1<<<782, 256, 0, stream>>>(Anode, W1csw + 2 * 32768, cb1, H1RC);
  hipMemsetAsync(pagg, 0, (size_t)NN * 3 * 4, stream);
  k_edge_gemm<1><<<12500, 256, 0, stream>>>(H1RC, eaF8, rowS, colS,
      W1f8 + 2 * 36864, W2sw + 2 * 16384, cb2, cW3, (const float*)nullptr, ndS, pagg);
  k_pos_final<<<587, 256, 0, stream>>>(pos, mask, pagg, pout_f);
}

// Round 4
// 712.194 us; speedup vs baseline: 1.2485x; 1.0117x over previous
//
#include <hip/hip_runtime.h>
#include <hip/hip_bf16.h>
#include <stdint.h>

#define NN 50000
#define NE 800000
#define HH 128

typedef __bf16 bf16x8 __attribute__((ext_vector_type(8)));
typedef float  f32x4  __attribute__((ext_vector_type(4)));
typedef long   f8frag;   // 8 fp8 bytes = i64 MFMA operand

__device__ __forceinline__ unsigned short f2bf(float f) {
  union { float f; uint32_t u; } v; v.f = f;
  uint32_t r = v.u + 0x7FFFu + ((v.u >> 16) & 1u);
  return (unsigned short)(r >> 16);
}
__device__ __forceinline__ float b2f(unsigned short u) {
  union { float f; uint32_t u; } v; v.u = (uint32_t)u << 16; return v.f;
}
#if __has_builtin(__builtin_amdgcn_cvt_pk_bf16_f32)
typedef __bf16 bf16x2 __attribute__((ext_vector_type(2)));
__device__ __forceinline__ uint32_t pack2bf(float a, float b) {
  union { bf16x2 v; uint32_t u; } t;
  t.v = __builtin_amdgcn_cvt_pk_bf16_f32(a, b);
  return t.u;
}
#else
__device__ __forceinline__ uint32_t pack2bf(float a, float b) {
  return (uint32_t)f2bf(a) | ((uint32_t)f2bf(b) << 16);
}
#endif
__device__ __forceinline__ uint8_t f2fp8(float v) {
  return (uint8_t)(__builtin_amdgcn_cvt_pk_fp8_f32(v, 0.f, 0, false) & 0xff);
}
// fast silu/sigmoid
__device__ __forceinline__ float silu_f(float x) {
  return x * __builtin_amdgcn_rcpf(1.f + __expf(-x));
}
__device__ __forceinline__ float sigm_f(float x) {
  return __builtin_amdgcn_rcpf(1.f + __expf(-x));
}

// LDS tile blocks (bf16): [rows][32 k], 16B chunk c stored at c ^ ((row>>1)&3)
__device__ __forceinline__ bf16x8 frag_ld(const short* blk, int row, int q) {
  int c = q ^ ((row >> 1) & 3);
  return *(const bf16x8*)(blk + row * 32 + c * 8);
}
// bf16 global weight frag offset (swizzled prep layout, short-indexed)
__device__ __forceinline__ int wfrag_off(int row, int q) {
  return row * 32 + ((q ^ ((row >> 1) & 3)) * 8);
}
// build bf16x8 frag from 8 consecutive f32 (16B-aligned), with scale folded
__device__ __forceinline__ bf16x8 fragf32(const float* src, float sc) {
  float4 lo = *(const float4*)src;
  float4 hi = *(const float4*)(src + 4);
  union { uint32_t u[4]; bf16x8 v; } t;
  t.u[0] = pack2bf(lo.x * sc, lo.y * sc);
  t.u[1] = pack2bf(lo.z * sc, lo.w * sc);
  t.u[2] = pack2bf(hi.x * sc, hi.y * sc);
  t.u[3] = pack2bf(hi.z * sc, hi.w * sc);
  return t.v;
}

// ---------------- weight prep ----------------
// W1f8: 3 sets x [9 kk][128 n][32 k] fp8 (only kk=8 / ea block used by edge kernel)
// W2sw: 3 sets bf16 swizzled; Wn1sw/Wn2sw: 2 sets bf16 swizzled
// W1csw: 3 sets x [4 kk][256 n][32 k] bf16 swizzled (Wcat for per-node H1 GEMM)
__global__ void k_prep_weights(const float* We1, const float* We2, const float* Wn1,
                               const float* Wn2, const float* cW1, const float* cW2,
                               uint8_t* W1f8, short* W2sw, short* Wn1sw, short* Wn2sw,
                               short* W1csw) {
  int idx = blockIdx.x * 256 + threadIdx.x;
  if (idx < 110592) {                      // fp8 W1 (ks=265)
    int l = idx / 36864, rem = idx % 36864;
    const float* s = (l == 0) ? We1 : (l == 1) ? We1 + 33920 : cW1;
    int kkb = rem >> 12, r2 = rem & 4095;
    int n = r2 >> 5, kw = r2 & 31;
    int k = kkb * 32 + kw;
    float v = (k < 265) ? s[k * 128 + n] : 0.f;
    W1f8[idx] = f2fp8(v);
    return;
  }
  idx -= 110592;
  if (idx < 49152) {                       // bf16 W2, 3 sets, ks=128
    int l = idx >> 14, rem = idx & 16383;
    const float* s = (l == 0) ? We2 : (l == 1) ? We2 + 16384 : cW2;
    int kkb = rem >> 12, r2 = rem & 4095, n = r2 >> 5, kw = r2 & 31;
    int cp = kw >> 3, j = kw & 7, c = cp ^ ((n >> 1) & 3);
    int k = kkb * 32 + c * 8 + j;
    W2sw[(l << 14) + (rem)] = (short)f2bf(s[k * 128 + n]);
    return;
  }
  idx -= 49152;
  if (idx < 65536) {                       // bf16 Wn1, 2 sets, ks=256
    int l = idx >> 15, rem = idx & 32767;
    const float* s = Wn1 + l * 32768;
    int kkb = rem >> 12, r2 = rem & 4095, n = r2 >> 5, kw = r2 & 31;
    int cp = kw >> 3, j = kw & 7, c = cp ^ ((n >> 1) & 3);
    int k = kkb * 32 + c * 8 + j;
    Wn1sw[(l << 15) + rem] = (short)f2bf(s[k * 128 + n]);
    return;
  }
  idx -= 65536;
  if (idx < 32768) {                       // bf16 Wn2, 2 sets, ks=128
    int l = idx >> 14, rem = idx & 16383;
    const float* s = Wn2 + l * 16384;
    int kkb = rem >> 12, r2 = rem & 4095, n = r2 >> 5, kw = r2 & 31;
    int cp = kw >> 3, j = kw & 7, c = cp ^ ((n >> 1) & 3);
    int k = kkb * 32 + c * 8 + j;
    Wn2sw[(l << 14) + rem] = (short)f2bf(s[k * 128 + n]);
    return;
  }
  idx -= 32768;
  if (idx < 98304) {                       // bf16 W1cat, 3 sets, [4kk][256n][32k]
    int l = idx / 32768, rem = idx % 32768;
    const float* s = (l == 0) ? We1 : (l == 1) ? We1 + 33920 : cW1;
    int kkb = rem >> 13, r2 = rem & 8191, n = r2 >> 5, kw = r2 & 31;
    int cp = kw >> 3, j = kw & 7, c = cp ^ ((n >> 1) & 3);
    int k = kkb * 32 + c * 8 + j;          // 0..127
    float v = (n < 128) ? s[k * 128 + n] : s[(128 + k) * 128 + (n - 128)];
    W1csw[l * 32768 + rem] = (short)f2bf(v);
  }
}

// ---------------- small prep / epilogue kernels ----------------
// after sort: original-order streaming reads, scatter-writes into sorted slots
__global__ void k_edge_pre(const float* __restrict__ pos, const float* __restrict__ eattr,
                           const int* __restrict__ ei, const int* __restrict__ inv,
                           int* __restrict__ rowS, int* __restrict__ colS,
                           uint8_t* __restrict__ eaF8, float* __restrict__ ndS) {
  int e = blockIdx.x * 256 + threadIdx.x;
  if (e >= NE) return;
  int r = ei[e], c = ei[NE + e];
  float dx = pos[r * 3 + 0] - pos[c * 3 + 0];
  float dy = pos[r * 3 + 1] - pos[c * 3 + 1];
  float dz = pos[r * 3 + 2] - pos[c * 3 + 2];
  float d2 = dx * dx + dy * dy + dz * dz;
  float invd = __builtin_amdgcn_rcpf(sqrtf(d2) + 1.f);   // NC = 1.0
  int p = inv[e];
  rowS[p] = r;
  colS[p] = c;
  ndS[p * 3 + 0] = dx * invd;
  ndS[p * 3 + 1] = dy * invd;
  ndS[p * 3 + 2] = dz * invd;
  const float* ea = eattr + (size_t)e * 8;
  uint32_t w0 = __builtin_amdgcn_cvt_pk_fp8_f32(d2, ea[0], 0, false);
  w0 = __builtin_amdgcn_cvt_pk_fp8_f32(ea[1], ea[2], w0, true);
  uint32_t w1 = __builtin_amdgcn_cvt_pk_fp8_f32(ea[3], ea[4], 0, false);
  w1 = __builtin_amdgcn_cvt_pk_fp8_f32(ea[5], ea[6], w1, true);
  uint32_t w2 = __builtin_amdgcn_cvt_pk_fp8_f32(ea[7], 0.f, 0, false);
  uint4 v = {w0, w1, w2, 0u};
  *(uint4*)(eaF8 + (size_t)p * 16) = v;
}
__global__ void k_pos_final(const float* __restrict__ pos, const float* __restrict__ mask,
                            const float* __restrict__ pagg, float* __restrict__ out) {
  int i = blockIdx.x * 256 + threadIdx.x;
  if (i < NN * 3) out[i] = pos[i] + pagg[i] * 0.01f * mask[i / 3];
}

// ---------------- CSR sort of edges by destination row ----------------
__global__ void k_hist(const int* __restrict__ ei, int* __restrict__ cnt) {
  int e = blockIdx.x * 256 + threadIdx.x;
  if (e < NE) atomicAdd(&cnt[ei[e]], 1);
}
__global__ void k_scan_block(const int* __restrict__ cnt, int* __restrict__ offs,
                             int* __restrict__ bsum) {
  __shared__ int s[256];
  int i = blockIdx.x * 256 + threadIdx.x;
  int v = (i < NN) ? cnt[i] : 0;
  s[threadIdx.x] = v;
  __syncthreads();
#pragma unroll
  for (int d = 1; d < 256; d <<= 1) {
    int t = (threadIdx.x >= d) ? s[threadIdx.x - d] : 0;
    __syncthreads();
    s[threadIdx.x] += t;
    __syncthreads();
  }
  if (i < NN) offs[i] = s[threadIdx.x] - v;
  if (threadIdx.x == 255) bsum[blockIdx.x] = s[255];
}
__global__ void k_scan_top(int* __restrict__ bsum) {
  __shared__ int s[256];
  int v = (threadIdx.x < 196) ? bsum[threadIdx.x] : 0;
  s[threadIdx.x] = v;
  __syncthreads();
#pragma unroll
  for (int d = 1; d < 256; d <<= 1) {
    int t = (threadIdx.x >= d) ? s[threadIdx.x - d] : 0;
    __syncthreads();
    s[threadIdx.x] += t;
    __syncthreads();
  }
  if (threadIdx.x < 196) bsum[threadIdx.x] = s[threadIdx.x] - v;
}
__global__ void k_scan_add(int* __restrict__ offs, const int* __restrict__ bsum) {
  int i = blockIdx.x * 256 + threadIdx.x;
  if (i < NN) offs[i] += bsum[blockIdx.x];
}
__global__ void k_scatter(const int* __restrict__ ei, int* __restrict__ offs,
                          int* __restrict__ inv) {
  int e = blockIdx.x * 256 + threadIdx.x;
  if (e < NE) inv[e] = atomicAdd(&offs[ei[e]], 1);
}

// ---------------- per-node H1 precompute (layer 0 only, reads x f32) ----------------
// H1RC[node][256] = bf16(x @ W1cat) (+b1 on low half). 64 nodes/block, 4 waves;
// wave w owns 64 output chans. Permuted store: within wave-64 block, logical
// chan (ni*16 + ln) stored at (ln*4 + ni) -> ushort4 stores; edge kernel reads
// 16 contiguous shorts per (wn,q) group.
__global__ __launch_bounds__(256) void k_h1(
    const float* __restrict__ x, const short* __restrict__ W1c,
    const float* __restrict__ b1, short* __restrict__ H1RC) {
  const int tid = threadIdx.x, lane = tid & 63, w = tid >> 6;
  const int ln = lane & 15, q = lane >> 4;
  const int tile = blockIdx.x;
  size_t nbase[4];
  int wofs[4];
#pragma unroll
  for (int i = 0; i < 4; ++i) {
    int node = tile * 64 + i * 16 + ln;
    nbase[i] = (size_t)(node < NN ? node : (NN - 1)) * 128;
    int row = w * 64 + i * 16 + ln;
    wofs[i] = row * 32 + ((q ^ ((row >> 1) & 3)) * 8);
  }
  f32x4 acc[4][4];
  const f32x4 zero4 = {0.f, 0.f, 0.f, 0.f};
#pragma unroll
  for (int mi = 0; mi < 4; ++mi)
#pragma unroll
    for (int ni = 0; ni < 4; ++ni) acc[mi][ni] = zero4;
#pragma unroll
  for (int kk = 0; kk < 4; ++kk) {
    bf16x8 af[4], bfr[4];
#pragma unroll
    for (int i = 0; i < 4; ++i) af[i] = fragf32(x + nbase[i] + kk * 32 + q * 8, 1.f);
#pragma unroll
    for (int i = 0; i < 4; ++i) bfr[i] = *(const bf16x8*)(W1c + kk * 8192 + wofs[i]);
#pragma unroll
    for (int mi = 0; mi < 4; ++mi)
#pragma unroll
      for (int ni = 0; ni < 4; ++ni)
        acc[mi][ni] = __builtin_amdgcn_mfma_f32_16x16x32_bf16(af[mi], bfr[ni], acc[mi][ni], 0, 0, 0);
  }
  float b1v[4];
#pragma unroll
  for (int ni = 0; ni < 4; ++ni) {
    int ch = w * 64 + ni * 16 + ln;
    b1v[ni] = (ch < 128) ? b1[ch] : 0.f;
  }
#pragma unroll
  for (int mi = 0; mi < 4; ++mi)
#pragma unroll
    for (int r = 0; r < 4; ++r) {
      int node = tile * 64 + mi * 16 + q * 4 + r;
      if (node < NN) {
        ushort4 pk;
        pk.x = f2bf(acc[mi][0][r] + b1v[0]);
        pk.y = f2bf(acc[mi][1][r] + b1v[1]);
        pk.z = f2bf(acc[mi][2][r] + b1v[2]);
        pk.w = f2bf(acc[mi][3][r] + b1v[3]);
        *(ushort4*)(H1RC + (size_t)node * 256 + w * 64 + ln * 4) = pk;
      }
    }
}

// ---------------- fused edge/coord MLP (edges presorted by row) ----------------
// h1 = silu(H1RC[row].lo + H1RC[col].hi + ea@W1ea)  -- per-node GEMM1 hoisted out.
// GEMM2/segment-sum in bf16. TRANSPOSED MFMA: D[chan][edge] (lane=edge).
// Attention folded into the segment-sum S matrix. XCD-bijective tile swizzle.
template <int COORD>
__global__ __launch_bounds__(256, 4) void k_edge_gemm(
    const short* __restrict__ H1RC, const uint8_t* __restrict__ eaF8,
    const int* __restrict__ rowS, const int* __restrict__ colS,
    const uint8_t* __restrict__ W1f8, const short* __restrict__ W2l,
    const float* __restrict__ b2,
    const float* __restrict__ wred, const float* __restrict__ batt,
    const float* __restrict__ ndS, float* outAcc) {
  __shared__ __align__(16) short A2s[8192];  // h1^T 4x[64e][32c]; then M 2x[128c][32e]
  __shared__ float redp[64][2];
  __shared__ __align__(16) unsigned short attb[64];
  __shared__ int srow[64];
  __shared__ __align__(8) unsigned char srunS[64];
  __shared__ int runrowS[64];
  __shared__ int cntS[1];

  const int tid = threadIdx.x;
  const int lane = tid & 63;
  const int w = tid >> 6;
  const int ln = lane & 15, q = lane >> 4;
  const int wm = w >> 1, wn = w & 1;

  // XCD-bijective swizzle (8 XCDs): consecutive tiles land on the same XCD's L2
  const int nwg = gridDim.x;
  const int qq = nwg >> 3, rr = nwg & 7;
  const int xcd = blockIdx.x & 7, bidx = blockIdx.x >> 3;
  const int tile = (xcd < rr ? xcd * (qq + 1) : rr * (qq + 1) + (xcd - rr) * qq) + bidx;

  if (tid < 64) srow[tid] = rowS[tile * 64 + tid];
  __syncthreads();

  // ---- segmented-run scan over sorted rows (wave 0 only) ----
  bool is_start = (tid < 64) && (tid == 0 || srow[tid] != srow[tid - 1]);
  unsigned long long bmask = __ballot(is_start);
  if (tid == 0) cntS[0] = __popcll(bmask);
  if (tid < 64) {
    int run = __popcll(bmask & ((1ull << lane) - 1ull)) + (is_start ? 1 : 0) - 1;
    srunS[tid] = (unsigned char)run;
    if (is_start) runrowS[run] = srow[tid];
  }
  // (published by epilogue1's barrier; read only after GEMM2)

  // per-lane sources (uint32 offsets -> saddr-form loads)
  const int e0 = wm * 32 + ln, e1 = e0 + 16;
  const uint32_t cbp = (uint32_t)(wn * 64 + q * 16);   // permuted chan-group base
  const uint32_t hr0 = (uint32_t)srow[e0] * 256u + cbp;
  const uint32_t hr1 = (uint32_t)srow[e1] * 256u + cbp;
  const uint32_t hc0 = (uint32_t)colS[tile * 64 + e0] * 256u + 128u + cbp;
  const uint32_t hc1 = (uint32_t)colS[tile * 64 + e1] * 256u + 128u + cbp;
  const uint32_t ea0 = (uint32_t)(tile * 64 + e0) * 16u + (uint32_t)((q & 1) * 8);
  const uint32_t ea1 = (uint32_t)(tile * 64 + e1) * 16u + (uint32_t)((q & 1) * 8);
  int wofs8[4], wofs[4];
#pragma unroll
  for (int i = 0; i < 4; ++i) {
    wofs8[i] = (wn * 64 + i * 16 + ln) * 32 + q * 8;      // fp8 bytes (ea block)
    wofs[i] = wfrag_off(wn * 64 + i * 16 + ln, q);        // bf16 shorts
  }

  // H1 gathers: 16B each; halves indexed by r>>1, value (ni,r) at s[(r&1)*4+ni]
  union U8 { uint4 v; unsigned short s[8]; };
  U8 xr[2][2], xc[2][2];
  xr[0][0].v = *(const uint4*)(H1RC + hr0);
  xr[0][1].v = *(const uint4*)(H1RC + hr0 + 8);
  xr[1][0].v = *(const uint4*)(H1RC + hr1);
  xr[1][1].v = *(const uint4*)(H1RC + hr1 + 8);
  xc[0][0].v = *(const uint4*)(H1RC + hc0);
  xc[0][1].v = *(const uint4*)(H1RC + hc0 + 8);
  xc[1][0].v = *(const uint4*)(H1RC + hc1);
  xc[1][1].v = *(const uint4*)(H1RC + hc1 + 8);

  f32x4 acc[4][2];                           // [chan-tile ni][edge-tile mi]
  const f32x4 zero4 = {0.f, 0.f, 0.f, 0.f};
#pragma unroll
  for (int ni = 0; ni < 4; ++ni)
#pragma unroll
    for (int mi = 0; mi < 2; ++mi) acc[ni][mi] = zero4;

  // -------- ea-only fp8 MFMA step (K=32 covering the 9 ea dims) --------
  {
    const uint8_t* W1ea = W1f8 + 8 * 4096;
    f8frag wf[4], hf[2];
#pragma unroll
    for (int i = 0; i < 4; ++i) wf[i] = *(const f8frag*)(W1ea + wofs8[i]);
    hf[0] = (q < 2) ? *(const f8frag*)(eaF8 + ea0) : 0L;
    hf[1] = (q < 2) ? *(const f8frag*)(eaF8 + ea1) : 0L;
#pragma unroll
    for (int ni = 0; ni < 4; ++ni)
#pragma unroll
      for (int mi = 0; mi < 2; ++mi)
        acc[ni][mi] = __builtin_amdgcn_mfma_f32_16x16x32_fp8_fp8(wf[ni], hf[mi], acc[ni][mi], 0, 0, 0);
  }

  // -------- epilogue1: silu(ea + H1R[row] + H1C[col]) -> A2s bf16 [edge][chan] --------
#pragma unroll
  for (int ni = 0; ni < 4; ++ni) {
    int cb = wn * 64 + ni * 16 + q * 4;            // 4 consecutive logical chans
    int kkb = cb >> 5, cc = (cb >> 3) & 3, j0 = cb & 7;
#pragma unroll
    for (int mi = 0; mi < 2; ++mi) {
      int edge = wm * 32 + mi * 16 + ln;
      int addr = kkb * 2048 + edge * 32 + ((cc ^ ((edge >> 1) & 3)) * 8) + j0;
      float h0 = silu_f(acc[ni][mi][0] + b2f(xr[mi][0].s[ni]) + b2f(xc[mi][0].s[ni]));
      float h1 = silu_f(acc[ni][mi][1] + b2f(xr[mi][0].s[4 + ni]) + b2f(xc[mi][0].s[4 + ni]));
      float h2 = silu_f(acc[ni][mi][2] + b2f(xr[mi][1].s[ni]) + b2f(xc[mi][1].s[ni]));
      float h3 = silu_f(acc[ni][mi][3] + b2f(xr[mi][1].s[4 + ni]) + b2f(xc[mi][1].s[4 + ni]));
      uint2 pk;
      pk.x = pack2bf(h0, h1);
      pk.y = pack2bf(h2, h3);
      *(uint2*)(A2s + addr) = pk;
    }
  }
  __syncthreads();

  // -------- GEMM2 (bf16): M^T[128c2 x 64e] = W2^T(A) x h1^T(B), barrier-free --------
  f32x4 acc2[4][2];
#pragma unroll
  for (int ni = 0; ni < 4; ++ni)
#pragma unroll
    for (int mi = 0; mi < 2; ++mi) acc2[ni][mi] = zero4;
#pragma unroll
  for (int kk = 0; kk < 4; ++kk) {
    bf16x8 wf[4], hf[2];
#pragma unroll
    for (int i = 0; i < 4; ++i) wf[i] = *(const bf16x8*)(W2l + kk * 4096 + wofs[i]);
#pragma unroll
    for (int i = 0; i < 2; ++i) hf[i] = frag_ld(A2s + kk * 2048, wm * 32 + i * 16 + ln, q);
#pragma unroll
    for (int ni = 0; ni < 4; ++ni)
#pragma unroll
      for (int mi = 0; mi < 2; ++mi)
        acc2[ni][mi] = __builtin_amdgcn_mfma_f32_16x16x32_bf16(wf[ni], hf[mi], acc2[ni][mi], 0, 0, 0);
  }

  // -------- epilogue2: silu + attention/phi dot (mostly in-lane) --------
  float4 b2v[4], wv[4];
#pragma unroll
  for (int ni = 0; ni < 4; ++ni) {
    b2v[ni] = *(const float4*)(b2 + wn * 64 + ni * 16 + q * 4);
    wv[ni]  = *(const float4*)(wred + wn * 64 + ni * 16 + q * 4);
  }
  float p[2] = {0.f, 0.f};
#pragma unroll
  for (int ni = 0; ni < 4; ++ni)
#pragma unroll
    for (int mi = 0; mi < 2; ++mi)
#pragma unroll
      for (int r = 0; r < 4; ++r) {
        float v = silu_f(acc2[ni][mi][r] + ((const float*)&b2v[ni])[r]);
        acc2[ni][mi][r] = v;
        p[mi] += v * ((const float*)&wv[ni])[r];
      }
#pragma unroll
  for (int mi = 0; mi < 2; ++mi) {
    p[mi] += __shfl_xor(p[mi], 16, 64);
    p[mi] += __shfl_xor(p[mi], 32, 64);
  }
  if (lane < 16) {
#pragma unroll
    for (int mi = 0; mi < 2; ++mi) redp[wm * 32 + mi * 16 + ln][wn] = p[mi];
  }
  __syncthreads();   // redp ready; all waves done with A2s (GEMM2)

  if (COORD == 0) {
    if (tid < 64) attb[tid] = f2bf(sigm_f(redp[tid][0] + redp[tid][1] + batt[0]));
    // M-tile 2x[128 chan][32 edge] swizzled blocks (B-operand layout for S-GEMM),
    // UNscaled -- attention rides in the S matrix.
#pragma unroll
    for (int ni = 0; ni < 4; ++ni)
#pragma unroll
      for (int mi = 0; mi < 2; ++mi) {
        int eb = mi * 16 + ln;
        int cE = (eb >> 3) & 3, jE = eb & 7;
#pragma unroll
        for (int r = 0; r < 4; ++r) {
          int chan2 = wn * 64 + ni * 16 + q * 4 + r;
          int addr = wm * 4096 + chan2 * 32 + ((cE ^ ((chan2 >> 1) & 3)) * 8) + jE;
          union { float f; uint32_t u; } vv;
          vv.f = acc2[ni][mi][r];
          A2s[addr] = (short)((vv.u + 0x8000u) >> 16);   // round-half-up to bf16
        }
      }
    __syncthreads();   // attb + M ready
    // segment-sum via MFMA: agg[run][chan] = S[run][edge] @ M[edge][chan]
    const int nruns = cntS[0];
    bf16x8 bfrg[2][2];
#pragma unroll
    for (int kk = 0; kk < 2; ++kk)
#pragma unroll
      for (int ni = 0; ni < 2; ++ni)
        bfrg[kk][ni] = frag_ld(A2s + kk * 4096, w * 32 + ni * 16 + ln, q);
    const int npass = (nruns + 15) >> 4;
    for (int pp = 0; pp < npass; ++pp) {
      const unsigned int base = pp * 16;
      f32x4 a3c[2] = {zero4, zero4};
#pragma unroll
      for (int kk = 0; kk < 2; ++kk) {
        uint2 sb = *(const uint2*)(srunS + kk * 32 + q * 8);
        U8 ab;
        ab.v = *(const uint4*)(attb + kk * 32 + q * 8);
        union { short s[8]; bf16x8 v; } af;
#pragma unroll
        for (int j = 0; j < 4; ++j)
          af.s[j] = (((sb.x >> (8 * j)) & 255u) == base + (unsigned)ln) ? (short)ab.s[j] : (short)0;
#pragma unroll
        for (int j = 0; j < 4; ++j)
          af.s[4 + j] = (((sb.y >> (8 * j)) & 255u) == base + (unsigned)ln) ? (short)ab.s[4 + j] : (short)0;
        a3c[0] = __builtin_amdgcn_mfma_f32_16x16x32_bf16(af.v, bfrg[kk][0], a3c[0], 0, 0, 0);
        a3c[1] = __builtin_amdgcn_mfma_f32_16x16x32_bf16(af.v, bfrg[kk][1], a3c[1], 0, 0, 0);
      }
#pragma unroll
      for (int ni = 0; ni < 2; ++ni)
#pragma unroll
        for (int r = 0; r < 4; ++r) {
          int run = (int)base + q * 4 + r;
          if (run < nruns) {
            int rw = runrowS[run];
            atomicAdd(&outAcc[(size_t)rw * 128 + (w * 32 + ni * 16 + ln)], a3c[ni][r]);
          }
        }
    }
  } else {
    float* ndl = (float*)A2s;   // reuse: [64][3]
    if (tid < 64) {
      float phi = redp[tid][0] + redp[tid][1];
      ndl[tid * 3 + 0] = ndS[(size_t)(tile * 64 + tid) * 3 + 0] * phi;
      ndl[tid * 3 + 1] = ndS[(size_t)(tile * 64 + tid) * 3 + 1] * phi;
      ndl[tid * 3 + 2] = ndS[(size_t)(tile * 64 + tid) * 3 + 2] * phi;
    }
    __syncthreads();
    if (is_start) {   // run-start walkers (tid<64 implied)
      int myrow = srow[tid];
      float s0 = 0.f, s1 = 0.f, s2 = 0.f;
      for (int j = tid; j < 64 && srow[j] == myrow; ++j) {
        s0 += ndl[j * 3 + 0];
        s1 += ndl[j * 3 + 1];
        s2 += ndl[j * 3 + 2];
      }
      atomicAdd(&outAcc[myrow * 3 + 0], s0);
      atomicAdd(&outAcc[myrow * 3 + 1], s1);
      atomicAdd(&outAcc[myrow * 3 + 2], s2);
    }
  }
}

// ---------------- node MLP GEMM + fused next-layer H1 (64-node tiles, bf16) ----------
// Reads BOTH K-halves from f32 (xres / agg*0.01) -- Anode buffer eliminated.
// After residual update, stages bf16(xnew) in LDS and computes next-stage
// H1RC = xnew @ W1cN (+b1N low half), permuted ushort4 stores.
__global__ __launch_bounds__(256) void k_node_gemm(
    const float* __restrict__ agg,
    const short* __restrict__ Wn1l, const short* __restrict__ Wn2l,
    const float* __restrict__ b1, const float* __restrict__ b2,
    const float* __restrict__ xres, float* __restrict__ xout,
    const short* __restrict__ W1cN, const float* __restrict__ b1N,
    short* __restrict__ H1RC) {
  __shared__ short A2s[4 * 2048];   // h1 staging [4kk][64 m][32 k]; then xnew staging

  const int tid = threadIdx.x;
  const int lane = tid & 63;
  const int w = tid >> 6;
  const int ln = lane & 15, q = lane >> 4;
  const int wm = w >> 1, wn = w & 1;
  const int tile = blockIdx.x;

  size_t nbase[2];
  int wofs[4];
#pragma unroll
  for (int i = 0; i < 2; ++i) {
    int node = tile * 64 + wm * 32 + i * 16 + ln;
    nbase[i] = (size_t)(node < NN ? node : (NN - 1)) * 128;
  }
#pragma unroll
  for (int i = 0; i < 4; ++i) wofs[i] = wfrag_off(wn * 64 + i * 16 + ln, q);

  f32x4 acc[2][4];
  const f32x4 zero4 = {0.f, 0.f, 0.f, 0.f};
#pragma unroll
  for (int mi = 0; mi < 2; ++mi)
#pragma unroll
    for (int ni = 0; ni < 4; ++ni) acc[mi][ni] = zero4;

#pragma unroll
  for (int kk = 0; kk < 8; ++kk) {
    bf16x8 af[2], bfr[4];
#pragma unroll
    for (int i = 0; i < 2; ++i) {
      if (kk < 4) af[i] = fragf32(xres + nbase[i] + kk * 32 + q * 8, 1.f);
      else        af[i] = fragf32(agg + nbase[i] + (kk - 4) * 32 + q * 8, 0.01f);
    }
#pragma unroll
    for (int i = 0; i < 4; ++i) bfr[i] = *(const bf16x8*)(Wn1l + kk * 4096 + wofs[i]);
#pragma unroll
    for (int mi = 0; mi < 2; ++mi)
#pragma unroll
      for (int ni = 0; ni < 4; ++ni)
        acc[mi][ni] = __builtin_amdgcn_mfma_f32_16x16x32_bf16(af[mi], bfr[ni], acc[mi][ni], 0, 0, 0);
  }

  float b1v[4];
#pragma unroll
  for (int ni = 0; ni < 4; ++ni) b1v[ni] = b1[wn * 64 + ni * 16 + ln];
#pragma unroll
  for (int mi = 0; mi < 2; ++mi)
#pragma unroll
    for (int ni = 0; ni < 4; ++ni) {
      int chan = wn * 64 + ni * 16 + ln;
      int kkb = chan >> 5, c = (chan >> 3) & 3, jj = chan & 7;
#pragma unroll
      for (int r = 0; r < 4; ++r) {
        int m = wm * 32 + mi * 16 + q * 4 + r;
        float v = silu_f(acc[mi][ni][r] + b1v[ni]);
        A2s[kkb * 2048 + m * 32 + ((c ^ ((m >> 1) & 3)) * 8) + jj] = (short)f2bf(v);
      }
    }
  __syncthreads();

  f32x4 acc2[2][4];
#pragma unroll
  for (int mi = 0; mi < 2; ++mi)
#pragma unroll
    for (int ni = 0; ni < 4; ++ni) acc2[mi][ni] = zero4;
#pragma unroll
  for (int kk = 0; kk < 4; ++kk) {
    bf16x8 af[2], bfr[4];
#pragma unroll
    for (int i = 0; i < 2; ++i) af[i] = frag_ld(A2s + kk * 2048, wm * 32 + i * 16 + ln, q);
#pragma unroll
    for (int i = 0; i < 4; ++i) bfr[i] = *(const bf16x8*)(Wn2l + kk * 4096 + wofs[i]);
#pragma unroll
    for (int mi = 0; mi < 2; ++mi)
#pragma unroll
      for (int ni = 0; ni < 4; ++ni)
        acc2[mi][ni] = __builtin_amdgcn_mfma_f32_16x16x32_bf16(af[mi], bfr[ni], acc2[mi][ni], 0, 0, 0);
  }

  // epilogue: residual add, write xout f32, keep xnew in acc2
  float b2v[4];
#pragma unroll
  for (int ni = 0; ni < 4; ++ni) b2v[ni] = b2[wn * 64 + ni * 16 + ln];
#pragma unroll
  for (int mi = 0; mi < 2; ++mi)
#pragma unroll
    for (int r = 0; r < 4; ++r) {
      int m = wm * 32 + mi * 16 + q * 4 + r;
      int node = tile * 64 + m;
      if (node < NN) {
#pragma unroll
        for (int ni = 0; ni < 4; ++ni) {
          int chan = wn * 64 + ni * 16 + ln;
          float v = acc2[mi][ni][r] + b2v[ni] + xres[(size_t)node * 128 + chan];
          acc2[mi][ni][r] = v;
          xout[(size_t)node * 128 + chan] = v;
        }
      }
    }

  // ---- fused H1 for the next stage: stage bf16(xnew) then GEMM vs W1cN ----
  __syncthreads();   // all GEMM2 reads of A2s done
#pragma unroll
  for (int mi = 0; mi < 2; ++mi)
#pragma unroll
    for (int ni = 0; ni < 4; ++ni) {
      int chan = wn * 64 + ni * 16 + ln;
      int kkb = chan >> 5, c = (chan >> 3) & 3, jj = chan & 7;
#pragma unroll
      for (int r = 0; r < 4; ++r) {
        int m = wm * 32 + mi * 16 + q * 4 + r;
        A2s[kkb * 2048 + m * 32 + ((c ^ ((m >> 1) & 3)) * 8) + jj] = (short)f2bf(acc2[mi][ni][r]);
      }
    }
  __syncthreads();

  int wofsH[4];
#pragma unroll
  for (int i = 0; i < 4; ++i) {
    int row = w * 64 + i * 16 + ln;
    wofsH[i] = row * 32 + ((q ^ ((row >> 1) & 3)) * 8);
  }
  f32x4 acc3[4][4];
#pragma unroll
  for (int mi = 0; mi < 4; ++mi)
#pragma unroll
    for (int ni = 0; ni < 4; ++ni) acc3[mi][ni] = zero4;
#pragma unroll
  for (int kk = 0; kk < 4; ++kk) {
    bf16x8 af[4], bfr[4];
#pragma unroll
    for (int i = 0; i < 4; ++i) af[i] = frag_ld(A2s + kk * 2048, i * 16 + ln, q);
#pragma unroll
    for (int i = 0; i < 4; ++i) bfr[i] = *(const bf16x8*)(W1cN + kk * 8192 + wofsH[i]);
#pragma unroll
    for (int mi = 0; mi < 4; ++mi)
#pragma unroll
      for (int ni = 0; ni < 4; ++ni)
        acc3[mi][ni] = __builtin_amdgcn_mfma_f32_16x16x32_bf16(af[mi], bfr[ni], acc3[mi][ni], 0, 0, 0);
  }
  float b1v2[4];
#pragma unroll
  for (int ni = 0; ni < 4; ++ni) {
    int ch = w * 64 + ni * 16 + ln;
    b1v2[ni] = (ch < 128) ? b1N[ch] : 0.f;
  }
#pragma unroll
  for (int mi = 0; mi < 4; ++mi)
#pragma unroll
    for (int r = 0; r < 4; ++r) {
      int node = tile * 64 + mi * 16 + q * 4 + r;
      if (node < NN) {
        ushort4 pk;
        pk.x = f2bf(acc3[mi][0][r] + b1v2[0]);
        pk.y = f2bf(acc3[mi][1][r] + b1v2[1]);
        pk.z = f2bf(acc3[mi][2][r] + b1v2[2]);
        pk.w = f2bf(acc3[mi][3][r] + b1v2[3]);
        *(ushort4*)(H1RC + (size_t)node * 256 + w * 64 + ln * 4) = pk;
      }
    }
}

extern "C" void kernel_launch(void* const* d_in, const int* in_sizes, int n_in,
                              void* d_out, int out_size, void* d_ws, size_t ws_size,
                              hipStream_t stream) {
  const float* x    = (const float*)d_in[0];
  const float* pos  = (const float*)d_in[1];
  const float* mask = (const float*)d_in[2];
  const float* eattr= (const float*)d_in[3];
  const int*   ei   = (const int*)d_in[4];
  const float* We1  = (const float*)d_in[5];
  const float* be1  = (const float*)d_in[6];
  const float* We2  = (const float*)d_in[7];
  const float* be2  = (const float*)d_in[8];
  const float* Watt = (const float*)d_in[9];
  const float* batt = (const float*)d_in[10];
  const float* Wn1  = (const float*)d_in[11];
  const float* bn1  = (const float*)d_in[12];
  const float* Wn2  = (const float*)d_in[13];
  const float* bn2  = (const float*)d_in[14];
  const float* cW1  = (const float*)d_in[15];
  const float* cb1  = (const float*)d_in[16];
  const float* cW2  = (const float*)d_in[17];
  const float* cb2  = (const float*)d_in[18];
  const float* cW3  = (const float*)d_in[19];

  char* p = (char*)d_ws;
  auto carve = [&](size_t bytes) { char* r = p; p += (bytes + 511) & ~(size_t)511; return r; };
  short*   H1RC  = (short*)carve((size_t)NN * 256 * 2);
  uint8_t* eaF8  = (uint8_t*)carve((size_t)NE * 16 + 256);
  int*     rowS  = (int*)carve((size_t)NE * 4);
  int*     colS  = (int*)carve((size_t)NE * 4);
  float*   ndS   = (float*)carve((size_t)NE * 3 * 4);
  float*   agg   = (float*)carve((size_t)NN * 128 * 4);
  float*   xcur  = (float*)carve((size_t)NN * 128 * 4);
  float*   pagg  = (float*)carve((size_t)NN * 3 * 4);
  uint8_t* W1f8  = (uint8_t*)carve(3 * 36864);
  short*   W2sw  = (short*)carve(3 * 16384 * 2);
  short*   Wn1sw = (short*)carve(2 * 32768 * 2);
  short*   Wn2sw = (short*)carve(2 * 16384 * 2);
  short*   W1csw = (short*)carve(3 * 32768 * 2);
  int*     cnt   = (int*)carve((size_t)NN * 4);
  int*     offs  = (int*)carve((size_t)NN * 4);
  int*     bsum  = (int*)carve(256 * 4);
  int*     inv   = (int*)carve((size_t)NE * 4);

  float* xout_f = (float*)d_out;        // N*128
  float* pout_f = xout_f + NN * 128;    // N*3

  k_prep_weights<<<1392, 256, 0, stream>>>(We1, We2, Wn1, Wn2, cW1, cW2,
                                           W1f8, W2sw, Wn1sw, Wn2sw, W1csw);

  // build row-sorted edge permutation (CSR order) -> inv[e] = sorted slot
  hipMemsetAsync(cnt, 0, (size_t)NN * 4, stream);
  k_hist<<<3125, 256, 0, stream>>>(ei, cnt);
  k_scan_block<<<196, 256, 0, stream>>>(cnt, offs, bsum);
  k_scan_top<<<1, 256, 0, stream>>>(bsum);
  k_scan_add<<<196, 256, 0, stream>>>(offs, bsum);
  k_scatter<<<3125, 256, 0, stream>>>(ei, offs, inv);
  k_edge_pre<<<3125, 256, 0, stream>>>(pos, eattr, ei, inv, rowS, colS, eaF8, ndS);

  // layer-0 H1 from x (f32)
  k_h1<<<782, 256, 0, stream>>>(x, W1csw, be1, H1RC);

  // layer 0
  hipMemsetAsync(agg, 0, (size_t)NN * 128 * 4, stream);
  k_edge_gemm<0><<<12500, 256, 0, stream>>>(H1RC, eaF8, rowS, colS,
      W1f8, W2sw, be2, Watt, batt, (const float*)nullptr, agg);
  k_node_gemm<<<782, 256, 0, stream>>>(agg, Wn1sw, Wn2sw, bn1, bn2,
      x, xcur, W1csw + 32768, be1 + 128, H1RC);

  // layer 1
  hipMemsetAsync(agg, 0, (size_t)NN * 128 * 4, stream);
  k_edge_gemm<0><<<12500, 256, 0, stream>>>(H1RC, eaF8, rowS, colS,
      W1f8 + 36864, W2sw + 16384, be2 + 128, Watt + 128, batt + 1,
      (const float*)nullptr, agg);
  k_node_gemm<<<782, 256, 0, stream>>>(agg, Wn1sw + 32768, Wn2sw + 16384,
      bn1 + 128, bn2 + 128, xcur, xout_f, W1csw + 2 * 32768, cb1, H1RC);

  // coord stage
  hipMemsetAsync(pagg, 0, (size_t)NN * 3 * 4, stream);
  k_edge_gemm<1><<<12500, 256, 0, stream>>>(H1RC, eaF8, rowS, colS,
      W1f8 + 2 * 36864, W2sw + 2 * 16384, cb2, cW3, (const float*)nullptr, ndS, pagg);
  k_pos_final<<<587, 256, 0, stream>>>(pos, mask, pagg, pout_f);
}

// Round 5
// 705.220 us; speedup vs baseline: 1.2609x; 1.0099x over previous
//
#include <hip/hip_runtime.h>
#include <hip/hip_bf16.h>
#include <stdint.h>

#define NN 50000
#define NE 800000
#define HH 128

typedef __bf16 bf16x8 __attribute__((ext_vector_type(8)));
typedef float  f32x4  __attribute__((ext_vector_type(4)));
typedef long   f8frag;   // 8 fp8 bytes = i64 MFMA operand

__device__ __forceinline__ unsigned short f2bf(float f) {
  union { float f; uint32_t u; } v; v.f = f;
  uint32_t r = v.u + 0x7FFFu + ((v.u >> 16) & 1u);
  return (unsigned short)(r >> 16);
}
__device__ __forceinline__ float b2f(unsigned short u) {
  union { float f; uint32_t u; } v; v.u = (uint32_t)u << 16; return v.f;
}
#if __has_builtin(__builtin_amdgcn_cvt_pk_bf16_f32)
typedef __bf16 bf16x2 __attribute__((ext_vector_type(2)));
__device__ __forceinline__ uint32_t pack2bf(float a, float b) {
  union { bf16x2 v; uint32_t u; } t;
  t.v = __builtin_amdgcn_cvt_pk_bf16_f32(a, b);
  return t.u;
}
#else
__device__ __forceinline__ uint32_t pack2bf(float a, float b) {
  return (uint32_t)f2bf(a) | ((uint32_t)f2bf(b) << 16);
}
#endif
__device__ __forceinline__ uint8_t f2fp8(float v) {
  return (uint8_t)(__builtin_amdgcn_cvt_pk_fp8_f32(v, 0.f, 0, false) & 0xff);
}
// fast silu/sigmoid
__device__ __forceinline__ float silu_f(float x) {
  return x * __builtin_amdgcn_rcpf(1.f + __expf(-x));
}
__device__ __forceinline__ float sigm_f(float x) {
  return __builtin_amdgcn_rcpf(1.f + __expf(-x));
}

// LDS tile blocks (bf16): [rows][32 k], 16B chunk c stored at c ^ ((row>>1)&3)
__device__ __forceinline__ bf16x8 frag_ld(const short* blk, int row, int q) {
  int c = q ^ ((row >> 1) & 3);
  return *(const bf16x8*)(blk + row * 32 + c * 8);
}
// bf16 global weight frag offset (swizzled prep layout, short-indexed)
__device__ __forceinline__ int wfrag_off(int row, int q) {
  return row * 32 + ((q ^ ((row >> 1) & 3)) * 8);
}
// build bf16x8 frag from 8 consecutive f32 (16B-aligned), with scale folded
__device__ __forceinline__ bf16x8 fragf32(const float* src, float sc) {
  float4 lo = *(const float4*)src;
  float4 hi = *(const float4*)(src + 4);
  union { uint32_t u[4]; bf16x8 v; } t;
  t.u[0] = pack2bf(lo.x * sc, lo.y * sc);
  t.u[1] = pack2bf(lo.z * sc, lo.w * sc);
  t.u[2] = pack2bf(hi.x * sc, hi.y * sc);
  t.u[3] = pack2bf(hi.z * sc, hi.w * sc);
  return t.v;
}

// ---------------- weight prep ----------------
__global__ void k_prep_weights(const float* We1, const float* We2, const float* Wn1,
                               const float* Wn2, const float* cW1, const float* cW2,
                               uint8_t* W1f8, short* W2sw, short* Wn1sw, short* Wn2sw,
                               short* W1csw) {
  int idx = blockIdx.x * 256 + threadIdx.x;
  if (idx < 110592) {                      // fp8 W1 (ks=265)
    int l = idx / 36864, rem = idx % 36864;
    const float* s = (l == 0) ? We1 : (l == 1) ? We1 + 33920 : cW1;
    int kkb = rem >> 12, r2 = rem & 4095;
    int n = r2 >> 5, kw = r2 & 31;
    int k = kkb * 32 + kw;
    float v = (k < 265) ? s[k * 128 + n] : 0.f;
    W1f8[idx] = f2fp8(v);
    return;
  }
  idx -= 110592;
  if (idx < 49152) {                       // bf16 W2, 3 sets, ks=128
    int l = idx >> 14, rem = idx & 16383;
    const float* s = (l == 0) ? We2 : (l == 1) ? We2 + 16384 : cW2;
    int kkb = rem >> 12, r2 = rem & 4095, n = r2 >> 5, kw = r2 & 31;
    int cp = kw >> 3, j = kw & 7, c = cp ^ ((n >> 1) & 3);
    int k = kkb * 32 + c * 8 + j;
    W2sw[(l << 14) + (rem)] = (short)f2bf(s[k * 128 + n]);
    return;
  }
  idx -= 49152;
  if (idx < 65536) {                       // bf16 Wn1, 2 sets, ks=256
    int l = idx >> 15, rem = idx & 32767;
    const float* s = Wn1 + l * 32768;
    int kkb = rem >> 12, r2 = rem & 4095, n = r2 >> 5, kw = r2 & 31;
    int cp = kw >> 3, j = kw & 7, c = cp ^ ((n >> 1) & 3);
    int k = kkb * 32 + c * 8 + j;
    Wn1sw[(l << 15) + rem] = (short)f2bf(s[k * 128 + n]);
    return;
  }
  idx -= 65536;
  if (idx < 32768) {                       // bf16 Wn2, 2 sets, ks=128
    int l = idx >> 14, rem = idx & 16383;
    const float* s = Wn2 + l * 16384;
    int kkb = rem >> 12, r2 = rem & 4095, n = r2 >> 5, kw = r2 & 31;
    int cp = kw >> 3, j = kw & 7, c = cp ^ ((n >> 1) & 3);
    int k = kkb * 32 + c * 8 + j;
    Wn2sw[(l << 14) + rem] = (short)f2bf(s[k * 128 + n]);
    return;
  }
  idx -= 32768;
  if (idx < 98304) {                       // bf16 W1cat, 3 sets, [4kk][256n][32k]
    int l = idx / 32768, rem = idx % 32768;
    const float* s = (l == 0) ? We1 : (l == 1) ? We1 + 33920 : cW1;
    int kkb = rem >> 13, r2 = rem & 8191, n = r2 >> 5, kw = r2 & 31;
    int cp = kw >> 3, j = kw & 7, c = cp ^ ((n >> 1) & 3);
    int k = kkb * 32 + c * 8 + j;          // 0..127
    float v = (n < 128) ? s[k * 128 + n] : s[(128 + k) * 128 + (n - 128)];
    W1csw[l * 32768 + rem] = (short)f2bf(v);
  }
}

// ---------------- small prep / epilogue kernels ----------------
// forward-perm version: per sorted slot p, gather original edge e = sortedIdx[p];
// ALL writes (rowS/colS/ndS/eaF8) are coalesced; reads are L2/L3-absorbed gathers.
__global__ void k_edge_pre(const float* __restrict__ pos, const float* __restrict__ eattr,
                           const int* __restrict__ ei, const int* __restrict__ sortedIdx,
                           int* __restrict__ rowS, int* __restrict__ colS,
                           uint8_t* __restrict__ eaF8, float* __restrict__ ndS) {
  int p = blockIdx.x * 256 + threadIdx.x;
  if (p >= NE) return;
  int e = sortedIdx[p];
  int r = ei[e], c = ei[NE + e];
  float dx = pos[r * 3 + 0] - pos[c * 3 + 0];
  float dy = pos[r * 3 + 1] - pos[c * 3 + 1];
  float dz = pos[r * 3 + 2] - pos[c * 3 + 2];
  float d2 = dx * dx + dy * dy + dz * dz;
  float invd = __builtin_amdgcn_rcpf(sqrtf(d2) + 1.f);   // NC = 1.0
  rowS[p] = r;
  colS[p] = c;
  ndS[p * 3 + 0] = dx * invd;
  ndS[p * 3 + 1] = dy * invd;
  ndS[p * 3 + 2] = dz * invd;
  const float* ea = eattr + (size_t)e * 8;
  uint32_t w0 = __builtin_amdgcn_cvt_pk_fp8_f32(d2, ea[0], 0, false);
  w0 = __builtin_amdgcn_cvt_pk_fp8_f32(ea[1], ea[2], w0, true);
  uint32_t w1 = __builtin_amdgcn_cvt_pk_fp8_f32(ea[3], ea[4], 0, false);
  w1 = __builtin_amdgcn_cvt_pk_fp8_f32(ea[5], ea[6], w1, true);
  uint32_t w2 = __builtin_amdgcn_cvt_pk_fp8_f32(ea[7], 0.f, 0, false);
  uint4 v = {w0, w1, w2, 0u};
  *(uint4*)(eaF8 + (size_t)p * 16) = v;
}
__global__ void k_pos_final(const float* __restrict__ pos, const float* __restrict__ mask,
                            const float* __restrict__ pagg, float* __restrict__ out) {
  int i = blockIdx.x * 256 + threadIdx.x;
  if (i < NN * 3) out[i] = pos[i] + pagg[i] * 0.01f * mask[i / 3];
}

// ---------------- CSR sort of edges by destination row ----------------
__global__ void k_hist(const int* __restrict__ ei, int* __restrict__ cnt) {
  int e = blockIdx.x * 256 + threadIdx.x;
  if (e < NE) atomicAdd(&cnt[ei[e]], 1);
}
__global__ void k_scan_block(const int* __restrict__ cnt, int* __restrict__ offs,
                             int* __restrict__ bsum) {
  __shared__ int s[256];
  int i = blockIdx.x * 256 + threadIdx.x;
  int v = (i < NN) ? cnt[i] : 0;
  s[threadIdx.x] = v;
  __syncthreads();
#pragma unroll
  for (int d = 1; d < 256; d <<= 1) {
    int t = (threadIdx.x >= d) ? s[threadIdx.x - d] : 0;
    __syncthreads();
    s[threadIdx.x] += t;
    __syncthreads();
  }
  if (i < NN) offs[i] = s[threadIdx.x] - v;
  if (threadIdx.x == 255) bsum[blockIdx.x] = s[255];
}
__global__ void k_scan_top(int* __restrict__ bsum) {
  __shared__ int s[256];
  int v = (threadIdx.x < 196) ? bsum[threadIdx.x] : 0;
  s[threadIdx.x] = v;
  __syncthreads();
#pragma unroll
  for (int d = 1; d < 256; d <<= 1) {
    int t = (threadIdx.x >= d) ? s[threadIdx.x - d] : 0;
    __syncthreads();
    s[threadIdx.x] += t;
    __syncthreads();
  }
  if (threadIdx.x < 196) bsum[threadIdx.x] = s[threadIdx.x] - v;
}
__global__ void k_scan_add(int* __restrict__ offs, const int* __restrict__ bsum) {
  int i = blockIdx.x * 256 + threadIdx.x;
  if (i < NN) offs[i] += bsum[blockIdx.x];
}
__global__ void k_scatter(const int* __restrict__ ei, int* __restrict__ offs,
                          int* __restrict__ sortedIdx) {
  int e = blockIdx.x * 256 + threadIdx.x;
  if (e < NE) sortedIdx[atomicAdd(&offs[ei[e]], 1)] = e;
}

// ---------------- per-node H1 precompute (layer 0 only, reads x f32) ----------------
// Also zeroes agg for its node range (replaces a hipMemsetAsync dispatch).
__global__ __launch_bounds__(256) void k_h1(
    const float* __restrict__ x, const short* __restrict__ W1c,
    const float* __restrict__ b1, short* __restrict__ H1RC,
    float* __restrict__ aggZ) {
  const int tid = threadIdx.x, lane = tid & 63, w = tid >> 6;
  const int ln = lane & 15, q = lane >> 4;
  const int tile = blockIdx.x;
  // zero agg tile (float4-coalesced)
  {
    float4* a4 = (float4*)aggZ;
    const float4 z4 = {0.f, 0.f, 0.f, 0.f};
#pragma unroll
    for (int k = 0; k < 8; ++k) {
      int i4 = tile * 2048 + k * 256 + tid;
      if (i4 < NN * 32) a4[i4] = z4;
    }
  }
  size_t nbase[4];
  int wofs[4];
#pragma unroll
  for (int i = 0; i < 4; ++i) {
    int node = tile * 64 + i * 16 + ln;
    nbase[i] = (size_t)(node < NN ? node : (NN - 1)) * 128;
    int row = w * 64 + i * 16 + ln;
    wofs[i] = row * 32 + ((q ^ ((row >> 1) & 3)) * 8);
  }
  f32x4 acc[4][4];
  const f32x4 zero4 = {0.f, 0.f, 0.f, 0.f};
#pragma unroll
  for (int mi = 0; mi < 4; ++mi)
#pragma unroll
    for (int ni = 0; ni < 4; ++ni) acc[mi][ni] = zero4;
#pragma unroll
  for (int kk = 0; kk < 4; ++kk) {
    bf16x8 af[4], bfr[4];
#pragma unroll
    for (int i = 0; i < 4; ++i) af[i] = fragf32(x + nbase[i] + kk * 32 + q * 8, 1.f);
#pragma unroll
    for (int i = 0; i < 4; ++i) bfr[i] = *(const bf16x8*)(W1c + kk * 8192 + wofs[i]);
#pragma unroll
    for (int mi = 0; mi < 4; ++mi)
#pragma unroll
      for (int ni = 0; ni < 4; ++ni)
        acc[mi][ni] = __builtin_amdgcn_mfma_f32_16x16x32_bf16(af[mi], bfr[ni], acc[mi][ni], 0, 0, 0);
  }
  float b1v[4];
#pragma unroll
  for (int ni = 0; ni < 4; ++ni) {
    int ch = w * 64 + ni * 16 + ln;
    b1v[ni] = (ch < 128) ? b1[ch] : 0.f;
  }
#pragma unroll
  for (int mi = 0; mi < 4; ++mi)
#pragma unroll
    for (int r = 0; r < 4; ++r) {
      int node = tile * 64 + mi * 16 + q * 4 + r;
      if (node < NN) {
        ushort4 pk;
        pk.x = f2bf(acc[mi][0][r] + b1v[0]);
        pk.y = f2bf(acc[mi][1][r] + b1v[1]);
        pk.z = f2bf(acc[mi][2][r] + b1v[2]);
        pk.w = f2bf(acc[mi][3][r] + b1v[3]);
        *(ushort4*)(H1RC + (size_t)node * 256 + w * 64 + ln * 4) = pk;
      }
    }
}

// ---------------- fused edge/coord MLP (edges presorted by row) ----------------
// h1 = silu(H1RC[row].lo + H1RC[col].hi + ea@W1ea). Attention rides in the
// segment-sum S matrix. XCD-bijective tile swizzle. Direct rowS/colS loads
// (no srow staging barrier); run-scan is wave0-private, published by the
// epilogue1 barrier.
template <int COORD>
__global__ __launch_bounds__(256, 5) void k_edge_gemm(
    const short* __restrict__ H1RC, const uint8_t* __restrict__ eaF8,
    const int* __restrict__ rowS, const int* __restrict__ colS,
    const uint8_t* __restrict__ W1f8, const short* __restrict__ W2l,
    const float* __restrict__ b2,
    const float* __restrict__ wred, const float* __restrict__ batt,
    const float* __restrict__ ndS, float* outAcc) {
  __shared__ __align__(16) short A2s[8192];  // h1^T 4x[64e][32c]; then M 2x[128c][32e]
  __shared__ float redp[64][2];
  __shared__ __align__(16) unsigned short attb[64];
  __shared__ int srow[64];
  __shared__ __align__(8) unsigned char srunS[64];
  __shared__ int runrowS[64];
  __shared__ int cntS[1];

  const int tid = threadIdx.x;
  const int lane = tid & 63;
  const int w = tid >> 6;
  const int ln = lane & 15, q = lane >> 4;
  const int wm = w >> 1, wn = w & 1;

  // XCD-bijective swizzle (8 XCDs): consecutive tiles land on the same XCD's L2
  const int nwg = gridDim.x;
  const int qq = nwg >> 3, rr = nwg & 7;
  const int xcd = blockIdx.x & 7, bidx = blockIdx.x >> 3;
  const int tile = (xcd < rr ? xcd * (qq + 1) : rr * (qq + 1) + (xcd - rr) * qq) + bidx;
  const int ebase = tile * 64;

  // ---- wave0: segmented-run scan over sorted rows (published by epilogue1 barrier)
  bool is_start = false;
  if (w == 0) {
    int myrow = rowS[ebase + tid];
    srow[tid] = myrow;                     // for COORD=1 walkers (same-wave use)
    int prevrow = (tid > 0) ? rowS[ebase + tid - 1] : (myrow ^ 1);
    is_start = (tid == 0) || (myrow != prevrow);
    unsigned long long bmask = __ballot(is_start);
    if (tid == 0) cntS[0] = __popcll(bmask);
    int run = __popcll(bmask & ((1ull << lane) - 1ull)) + (is_start ? 1 : 0) - 1;
    srunS[tid] = (unsigned char)run;
    if (is_start) runrowS[run] = myrow;
  }

  // per-lane sources (uint32 offsets -> saddr-form loads); direct global loads
  const int e0 = wm * 32 + ln, e1 = e0 + 16;
  const uint32_t cbp = (uint32_t)(wn * 64 + q * 16);   // permuted chan-group base
  const uint32_t hr0 = (uint32_t)rowS[ebase + e0] * 256u + cbp;
  const uint32_t hr1 = (uint32_t)rowS[ebase + e1] * 256u + cbp;
  const uint32_t hc0 = (uint32_t)colS[ebase + e0] * 256u + 128u + cbp;
  const uint32_t hc1 = (uint32_t)colS[ebase + e1] * 256u + 128u + cbp;
  const uint32_t ea0 = (uint32_t)(ebase + e0) * 16u + (uint32_t)((q & 1) * 8);
  const uint32_t ea1 = (uint32_t)(ebase + e1) * 16u + (uint32_t)((q & 1) * 8);
  int wofs8[4], wofs[4];
#pragma unroll
  for (int i = 0; i < 4; ++i) {
    wofs8[i] = (wn * 64 + i * 16 + ln) * 32 + q * 8;      // fp8 bytes (ea block)
    wofs[i] = wfrag_off(wn * 64 + i * 16 + ln, q);        // bf16 shorts
  }

  // H1 gathers: 16B each; halves indexed by r>>1, value (ni,r) at s[(r&1)*4+ni]
  union U8 { uint4 v; unsigned short s[8]; };
  U8 xr[2][2], xc[2][2];
  xr[0][0].v = *(const uint4*)(H1RC + hr0);
  xr[0][1].v = *(const uint4*)(H1RC + hr0 + 8);
  xr[1][0].v = *(const uint4*)(H1RC + hr1);
  xr[1][1].v = *(const uint4*)(H1RC + hr1 + 8);
  xc[0][0].v = *(const uint4*)(H1RC + hc0);
  xc[0][1].v = *(const uint4*)(H1RC + hc0 + 8);
  xc[1][0].v = *(const uint4*)(H1RC + hc1);
  xc[1][1].v = *(const uint4*)(H1RC + hc1 + 8);

  f32x4 acc[4][2];                           // [chan-tile ni][edge-tile mi]
  const f32x4 zero4 = {0.f, 0.f, 0.f, 0.f};
#pragma unroll
  for (int ni = 0; ni < 4; ++ni)
#pragma unroll
    for (int mi = 0; mi < 2; ++mi) acc[ni][mi] = zero4;

  // -------- ea-only fp8 MFMA step (K=32 covering the 9 ea dims) --------
  {
    const uint8_t* W1ea = W1f8 + 8 * 4096;
    f8frag wf[4], hf[2];
#pragma unroll
    for (int i = 0; i < 4; ++i) wf[i] = *(const f8frag*)(W1ea + wofs8[i]);
    hf[0] = (q < 2) ? *(const f8frag*)(eaF8 + ea0) : 0L;
    hf[1] = (q < 2) ? *(const f8frag*)(eaF8 + ea1) : 0L;
#pragma unroll
    for (int ni = 0; ni < 4; ++ni)
#pragma unroll
      for (int mi = 0; mi < 2; ++mi)
        acc[ni][mi] = __builtin_amdgcn_mfma_f32_16x16x32_fp8_fp8(wf[ni], hf[mi], acc[ni][mi], 0, 0, 0);
  }

  // -------- epilogue1: silu(ea + H1R[row] + H1C[col]) -> A2s bf16 [edge][chan] --------
#pragma unroll
  for (int ni = 0; ni < 4; ++ni) {
    int cb = wn * 64 + ni * 16 + q * 4;            // 4 consecutive logical chans
    int kkb = cb >> 5, cc = (cb >> 3) & 3, j0 = cb & 7;
#pragma unroll
    for (int mi = 0; mi < 2; ++mi) {
      int edge = wm * 32 + mi * 16 + ln;
      int addr = kkb * 2048 + edge * 32 + ((cc ^ ((edge >> 1) & 3)) * 8) + j0;
      float h0 = silu_f(acc[ni][mi][0] + b2f(xr[mi][0].s[ni]) + b2f(xc[mi][0].s[ni]));
      float h1 = silu_f(acc[ni][mi][1] + b2f(xr[mi][0].s[4 + ni]) + b2f(xc[mi][0].s[4 + ni]));
      float h2 = silu_f(acc[ni][mi][2] + b2f(xr[mi][1].s[ni]) + b2f(xc[mi][1].s[ni]));
      float h3 = silu_f(acc[ni][mi][3] + b2f(xr[mi][1].s[4 + ni]) + b2f(xc[mi][1].s[4 + ni]));
      uint2 pk;
      pk.x = pack2bf(h0, h1);
      pk.y = pack2bf(h2, h3);
      *(uint2*)(A2s + addr) = pk;
    }
  }
  __syncthreads();

  // -------- GEMM2 (bf16): M^T[128c2 x 64e] = W2^T(A) x h1^T(B), barrier-free --------
  f32x4 acc2[4][2];
#pragma unroll
  for (int ni = 0; ni < 4; ++ni)
#pragma unroll
    for (int mi = 0; mi < 2; ++mi) acc2[ni][mi] = zero4;
#pragma unroll
  for (int kk = 0; kk < 4; ++kk) {
    bf16x8 wf[4], hf[2];
#pragma unroll
    for (int i = 0; i < 4; ++i) wf[i] = *(const bf16x8*)(W2l + kk * 4096 + wofs[i]);
#pragma unroll
    for (int i = 0; i < 2; ++i) hf[i] = frag_ld(A2s + kk * 2048, wm * 32 + i * 16 + ln, q);
#pragma unroll
    for (int ni = 0; ni < 4; ++ni)
#pragma unroll
      for (int mi = 0; mi < 2; ++mi)
        acc2[ni][mi] = __builtin_amdgcn_mfma_f32_16x16x32_bf16(wf[ni], hf[mi], acc2[ni][mi], 0, 0, 0);
  }

  // -------- epilogue2: silu + attention/phi dot (mostly in-lane) --------
  float4 b2v[4], wv[4];
#pragma unroll
  for (int ni = 0; ni < 4; ++ni) {
    b2v[ni] = *(const float4*)(b2 + wn * 64 + ni * 16 + q * 4);
    wv[ni]  = *(const float4*)(wred + wn * 64 + ni * 16 + q * 4);
  }
  float p[2] = {0.f, 0.f};
#pragma unroll
  for (int ni = 0; ni < 4; ++ni)
#pragma unroll
    for (int mi = 0; mi < 2; ++mi)
#pragma unroll
      for (int r = 0; r < 4; ++r) {
        float v = silu_f(acc2[ni][mi][r] + ((const float*)&b2v[ni])[r]);
        acc2[ni][mi][r] = v;
        p[mi] += v * ((const float*)&wv[ni])[r];
      }
#pragma unroll
  for (int mi = 0; mi < 2; ++mi) {
    p[mi] += __shfl_xor(p[mi], 16, 64);
    p[mi] += __shfl_xor(p[mi], 32, 64);
  }
  if (lane < 16) {
#pragma unroll
    for (int mi = 0; mi < 2; ++mi) redp[wm * 32 + mi * 16 + ln][wn] = p[mi];
  }
  __syncthreads();   // redp ready; all waves done with A2s (GEMM2)

  if (COORD == 0) {
    if (tid < 64) attb[tid] = f2bf(sigm_f(redp[tid][0] + redp[tid][1] + batt[0]));
    // M-tile 2x[128 chan][32 edge] swizzled blocks (B-operand layout for S-GEMM)
#pragma unroll
    for (int ni = 0; ni < 4; ++ni)
#pragma unroll
      for (int mi = 0; mi < 2; ++mi) {
        int eb = mi * 16 + ln;
        int cE = (eb >> 3) & 3, jE = eb & 7;
#pragma unroll
        for (int r = 0; r < 4; ++r) {
          int chan2 = wn * 64 + ni * 16 + q * 4 + r;
          int addr = wm * 4096 + chan2 * 32 + ((cE ^ ((chan2 >> 1) & 3)) * 8) + jE;
          union { float f; uint32_t u; } vv;
          vv.f = acc2[ni][mi][r];
          A2s[addr] = (short)((vv.u + 0x8000u) >> 16);   // round-half-up to bf16
        }
      }
    __syncthreads();   // attb + M ready
    // segment-sum via MFMA: agg[run][chan] = S[run][edge] @ M[edge][chan]
    const int nruns = cntS[0];
    bf16x8 bfrg[2][2];
#pragma unroll
    for (int kk = 0; kk < 2; ++kk)
#pragma unroll
      for (int ni = 0; ni < 2; ++ni)
        bfrg[kk][ni] = frag_ld(A2s + kk * 4096, w * 32 + ni * 16 + ln, q);
    const int npass = (nruns + 15) >> 4;
    for (int pp = 0; pp < npass; ++pp) {
      const unsigned int base = pp * 16;
      f32x4 a3c[2] = {zero4, zero4};
#pragma unroll
      for (int kk = 0; kk < 2; ++kk) {
        uint2 sb = *(const uint2*)(srunS + kk * 32 + q * 8);
        U8 ab;
        ab.v = *(const uint4*)(attb + kk * 32 + q * 8);
        union { short s[8]; bf16x8 v; } af;
#pragma unroll
        for (int j = 0; j < 4; ++j)
          af.s[j] = (((sb.x >> (8 * j)) & 255u) == base + (unsigned)ln) ? (short)ab.s[j] : (short)0;
#pragma unroll
        for (int j = 0; j < 4; ++j)
          af.s[4 + j] = (((sb.y >> (8 * j)) & 255u) == base + (unsigned)ln) ? (short)ab.s[4 + j] : (short)0;
        a3c[0] = __builtin_amdgcn_mfma_f32_16x16x32_bf16(af.v, bfrg[kk][0], a3c[0], 0, 0, 0);
        a3c[1] = __builtin_amdgcn_mfma_f32_16x16x32_bf16(af.v, bfrg[kk][1], a3c[1], 0, 0, 0);
      }
#pragma unroll
      for (int ni = 0; ni < 2; ++ni)
#pragma unroll
        for (int r = 0; r < 4; ++r) {
          int run = (int)base + q * 4 + r;
          if (run < nruns) {
            int rw = runrowS[run];
            atomicAdd(&outAcc[(size_t)rw * 128 + (w * 32 + ni * 16 + ln)], a3c[ni][r]);
          }
        }
    }
  } else {
    float* ndl = (float*)A2s;   // reuse: [64][3]
    if (tid < 64) {
      float phi = redp[tid][0] + redp[tid][1];
      ndl[tid * 3 + 0] = ndS[(size_t)(ebase + tid) * 3 + 0] * phi;
      ndl[tid * 3 + 1] = ndS[(size_t)(ebase + tid) * 3 + 1] * phi;
      ndl[tid * 3 + 2] = ndS[(size_t)(ebase + tid) * 3 + 2] * phi;
    }
    __syncthreads();
    if (is_start) {   // run-start walkers (wave0 only)
      int myrow = srow[tid];
      float s0 = 0.f, s1 = 0.f, s2 = 0.f;
      for (int j = tid; j < 64 && srow[j] == myrow; ++j) {
        s0 += ndl[j * 3 + 0];
        s1 += ndl[j * 3 + 1];
        s2 += ndl[j * 3 + 2];
      }
      atomicAdd(&outAcc[myrow * 3 + 0], s0);
      atomicAdd(&outAcc[myrow * 3 + 1], s1);
      atomicAdd(&outAcc[myrow * 3 + 2], s2);
    }
  }
}

// ---------------- node MLP GEMM + fused next-layer H1 (64-node tiles, bf16) ----------
// Reads both K-halves from f32 (xres / agg*0.01); zeroes agg after reading
// (replaces next layer's memset) when aggZ != nullptr.
__global__ __launch_bounds__(256) void k_node_gemm(
    const float* __restrict__ agg,
    const short* __restrict__ Wn1l, const short* __restrict__ Wn2l,
    const float* __restrict__ b1, const float* __restrict__ b2,
    const float* __restrict__ xres, float* __restrict__ xout,
    const short* __restrict__ W1cN, const float* __restrict__ b1N,
    short* __restrict__ H1RC, float* __restrict__ aggZ) {
  __shared__ short A2s[4 * 2048];   // h1 staging [4kk][64 m][32 k]; then xnew staging

  const int tid = threadIdx.x;
  const int lane = tid & 63;
  const int w = tid >> 6;
  const int ln = lane & 15, q = lane >> 4;
  const int wm = w >> 1, wn = w & 1;
  const int tile = blockIdx.x;

  size_t nbase[2];
  int wofs[4];
#pragma unroll
  for (int i = 0; i < 2; ++i) {
    int node = tile * 64 + wm * 32 + i * 16 + ln;
    nbase[i] = (size_t)(node < NN ? node : (NN - 1)) * 128;
  }
#pragma unroll
  for (int i = 0; i < 4; ++i) wofs[i] = wfrag_off(wn * 64 + i * 16 + ln, q);

  f32x4 acc[2][4];
  const f32x4 zero4 = {0.f, 0.f, 0.f, 0.f};
#pragma unroll
  for (int mi = 0; mi < 2; ++mi)
#pragma unroll
    for (int ni = 0; ni < 4; ++ni) acc[mi][ni] = zero4;

#pragma unroll
  for (int kk = 0; kk < 8; ++kk) {
    bf16x8 af[2], bfr[4];
#pragma unroll
    for (int i = 0; i < 2; ++i) {
      if (kk < 4) af[i] = fragf32(xres + nbase[i] + kk * 32 + q * 8, 1.f);
      else        af[i] = fragf32(agg + nbase[i] + (kk - 4) * 32 + q * 8, 0.01f);
    }
#pragma unroll
    for (int i = 0; i < 4; ++i) bfr[i] = *(const bf16x8*)(Wn1l + kk * 4096 + wofs[i]);
#pragma unroll
    for (int mi = 0; mi < 2; ++mi)
#pragma unroll
      for (int ni = 0; ni < 4; ++ni)
        acc[mi][ni] = __builtin_amdgcn_mfma_f32_16x16x32_bf16(af[mi], bfr[ni], acc[mi][ni], 0, 0, 0);
  }

  // zero agg tile after reading (for next layer's accumulation)
  if (aggZ) {
    float4* a4 = (float4*)aggZ;
    const float4 z4 = {0.f, 0.f, 0.f, 0.f};
#pragma unroll
    for (int k = 0; k < 8; ++k) {
      int i4 = tile * 2048 + k * 256 + tid;
      if (i4 < NN * 32) a4[i4] = z4;
    }
  }

  float b1v[4];
#pragma unroll
  for (int ni = 0; ni < 4; ++ni) b1v[ni] = b1[wn * 64 + ni * 16 + ln];
#pragma unroll
  for (int mi = 0; mi < 2; ++mi)
#pragma unroll
    for (int ni = 0; ni < 4; ++ni) {
      int chan = wn * 64 + ni * 16 + ln;
      int kkb = chan >> 5, c = (chan >> 3) & 3, jj = chan & 7;
#pragma unroll
      for (int r = 0; r < 4; ++r) {
        int m = wm * 32 + mi * 16 + q * 4 + r;
        float v = silu_f(acc[mi][ni][r] + b1v[ni]);
        A2s[kkb * 2048 + m * 32 + ((c ^ ((m >> 1) & 3)) * 8) + jj] = (short)f2bf(v);
      }
    }
  __syncthreads();

  f32x4 acc2[2][4];
#pragma unroll
  for (int mi = 0; mi < 2; ++mi)
#pragma unroll
    for (int ni = 0; ni < 4; ++ni) acc2[mi][ni] = zero4;
#pragma unroll
  for (int kk = 0; kk < 4; ++kk) {
    bf16x8 af[2], bfr[4];
#pragma unroll
    for (int i = 0; i < 2; ++i) af[i] = frag_ld(A2s + kk * 2048, wm * 32 + i * 16 + ln, q);
#pragma unroll
    for (int i = 0; i < 4; ++i) bfr[i] = *(const bf16x8*)(Wn2l + kk * 4096 + wofs[i]);
#pragma unroll
    for (int mi = 0; mi < 2; ++mi)
#pragma unroll
      for (int ni = 0; ni < 4; ++ni)
        acc2[mi][ni] = __builtin_amdgcn_mfma_f32_16x16x32_bf16(af[mi], bfr[ni], acc2[mi][ni], 0, 0, 0);
  }

  // epilogue: residual add, write xout f32, keep xnew in acc2
  float b2v[4];
#pragma unroll
  for (int ni = 0; ni < 4; ++ni) b2v[ni] = b2[wn * 64 + ni * 16 + ln];
#pragma unroll
  for (int mi = 0; mi < 2; ++mi)
#pragma unroll
    for (int r = 0; r < 4; ++r) {
      int m = wm * 32 + mi * 16 + q * 4 + r;
      int node = tile * 64 + m;
      if (node < NN) {
#pragma unroll
        for (int ni = 0; ni < 4; ++ni) {
          int chan = wn * 64 + ni * 16 + ln;
          float v = acc2[mi][ni][r] + b2v[ni] + xres[(size_t)node * 128 + chan];
          acc2[mi][ni][r] = v;
          xout[(size_t)node * 128 + chan] = v;
        }
      }
    }

  // ---- fused H1 for the next stage: stage bf16(xnew) then GEMM vs W1cN ----
  __syncthreads();   // all GEMM2 reads of A2s done
#pragma unroll
  for (int mi = 0; mi < 2; ++mi)
#pragma unroll
    for (int ni = 0; ni < 4; ++ni) {
      int chan = wn * 64 + ni * 16 + ln;
      int kkb = chan >> 5, c = (chan >> 3) & 3, jj = chan & 7;
#pragma unroll
      for (int r = 0; r < 4; ++r) {
        int m = wm * 32 + mi * 16 + q * 4 + r;
        A2s[kkb * 2048 + m * 32 + ((c ^ ((m >> 1) & 3)) * 8) + jj] = (short)f2bf(acc2[mi][ni][r]);
      }
    }
  __syncthreads();

  int wofsH[4];
#pragma unroll
  for (int i = 0; i < 4; ++i) {
    int row = w * 64 + i * 16 + ln;
    wofsH[i] = row * 32 + ((q ^ ((row >> 1) & 3)) * 8);
  }
  f32x4 acc3[4][4];
#pragma unroll
  for (int mi = 0; mi < 4; ++mi)
#pragma unroll
    for (int ni = 0; ni < 4; ++ni) acc3[mi][ni] = zero4;
#pragma unroll
  for (int kk = 0; kk < 4; ++kk) {
    bf16x8 af[4], bfr[4];
#pragma unroll
    for (int i = 0; i < 4; ++i) af[i] = frag_ld(A2s + kk * 2048, i * 16 + ln, q);
#pragma unroll
    for (int i = 0; i < 4; ++i) bfr[i] = *(const bf16x8*)(W1cN + kk * 8192 + wofsH[i]);
#pragma unroll
    for (int mi = 0; mi < 4; ++mi)
#pragma unroll
      for (int ni = 0; ni < 4; ++ni)
        acc3[mi][ni] = __builtin_amdgcn_mfma_f32_16x16x32_bf16(af[mi], bfr[ni], acc3[mi][ni], 0, 0, 0);
  }
  float b1v2[4];
#pragma unroll
  for (int ni = 0; ni < 4; ++ni) {
    int ch = w * 64 + ni * 16 + ln;
    b1v2[ni] = (ch < 128) ? b1N[ch] : 0.f;
  }
#pragma unroll
  for (int mi = 0; mi < 4; ++mi)
#pragma unroll
    for (int r = 0; r < 4; ++r) {
      int node = tile * 64 + mi * 16 + q * 4 + r;
      if (node < NN) {
        ushort4 pk;
        pk.x = f2bf(acc3[mi][0][r] + b1v2[0]);
        pk.y = f2bf(acc3[mi][1][r] + b1v2[1]);
        pk.z = f2bf(acc3[mi][2][r] + b1v2[2]);
        pk.w = f2bf(acc3[mi][3][r] + b1v2[3]);
        *(ushort4*)(H1RC + (size_t)node * 256 + w * 64 + ln * 4) = pk;
      }
    }
}

extern "C" void kernel_launch(void* const* d_in, const int* in_sizes, int n_in,
                              void* d_out, int out_size, void* d_ws, size_t ws_size,
                              hipStream_t stream) {
  const float* x    = (const float*)d_in[0];
  const float* pos  = (const float*)d_in[1];
  const float* mask = (const float*)d_in[2];
  const float* eattr= (const float*)d_in[3];
  const int*   ei   = (const int*)d_in[4];
  const float* We1  = (const float*)d_in[5];
  const float* be1  = (const float*)d_in[6];
  const float* We2  = (const float*)d_in[7];
  const float* be2  = (const float*)d_in[8];
  const float* Watt = (const float*)d_in[9];
  const float* batt = (const float*)d_in[10];
  const float* Wn1  = (const float*)d_in[11];
  const float* bn1  = (const float*)d_in[12];
  const float* Wn2  = (const float*)d_in[13];
  const float* bn2  = (const float*)d_in[14];
  const float* cW1  = (const float*)d_in[15];
  const float* cb1  = (const float*)d_in[16];
  const float* cW2  = (const float*)d_in[17];
  const float* cb2  = (const float*)d_in[18];
  const float* cW3  = (const float*)d_in[19];

  char* p = (char*)d_ws;
  auto carve = [&](size_t bytes) { char* r = p; p += (bytes + 511) & ~(size_t)511; return r; };
  short*   H1RC  = (short*)carve((size_t)NN * 256 * 2);
  uint8_t* eaF8  = (uint8_t*)carve((size_t)NE * 16 + 256);
  int*     rowS  = (int*)carve((size_t)NE * 4);
  int*     colS  = (int*)carve((size_t)NE * 4);
  float*   ndS   = (float*)carve((size_t)NE * 3 * 4);
  float*   agg   = (float*)carve((size_t)NN * 128 * 4);
  float*   xcur  = (float*)carve((size_t)NN * 128 * 4);
  float*   pagg  = (float*)carve((size_t)NN * 3 * 4);
  uint8_t* W1f8  = (uint8_t*)carve(3 * 36864);
  short*   W2sw  = (short*)carve(3 * 16384 * 2);
  short*   Wn1sw = (short*)carve(2 * 32768 * 2);
  short*   Wn2sw = (short*)carve(2 * 16384 * 2);
  short*   W1csw = (short*)carve(3 * 32768 * 2);
  int*     cnt   = (int*)carve((size_t)NN * 4);
  int*     offs  = (int*)carve((size_t)NN * 4);
  int*     bsum  = (int*)carve(256 * 4);
  int*     sortedIdx = (int*)carve((size_t)NE * 4);

  float* xout_f = (float*)d_out;        // N*128
  float* pout_f = xout_f + NN * 128;    // N*3

  k_prep_weights<<<1392, 256, 0, stream>>>(We1, We2, Wn1, Wn2, cW1, cW2,
                                           W1f8, W2sw, Wn1sw, Wn2sw, W1csw);

  // build row-sorted edge permutation (CSR order) -> sortedIdx[slot] = e
  hipMemsetAsync(cnt, 0, (size_t)NN * 4, stream);
  k_hist<<<3125, 256, 0, stream>>>(ei, cnt);
  k_scan_block<<<196, 256, 0, stream>>>(cnt, offs, bsum);
  k_scan_top<<<1, 256, 0, stream>>>(bsum);
  k_scan_add<<<196, 256, 0, stream>>>(offs, bsum);
  k_scatter<<<3125, 256, 0, stream>>>(ei, offs, sortedIdx);
  k_edge_pre<<<3125, 256, 0, stream>>>(pos, eattr, ei, sortedIdx, rowS, colS, eaF8, ndS);

  // layer-0 H1 from x (f32); also zeroes agg
  k_h1<<<782, 256, 0, stream>>>(x, W1csw, be1, H1RC, agg);

  // layer 0
  k_edge_gemm<0><<<12500, 256, 0, stream>>>(H1RC, eaF8, rowS, colS,
      W1f8, W2sw, be2, Watt, batt, (const float*)nullptr, agg);
  k_node_gemm<<<782, 256, 0, stream>>>(agg, Wn1sw, Wn2sw, bn1, bn2,
      x, xcur, W1csw + 32768, be1 + 128, H1RC, agg);   // zeroes agg for layer 1

  // layer 1
  k_edge_gemm<0><<<12500, 256, 0, stream>>>(H1RC, eaF8, rowS, colS,
      W1f8 + 36864, W2sw + 16384, be2 + 128, Watt + 128, batt + 1,
      (const float*)nullptr, agg);
  k_node_gemm<<<782, 256, 0, stream>>>(agg, Wn1sw + 32768, Wn2sw + 16384,
      bn1 + 128, bn2 + 128, xcur, xout_f, W1csw + 2 * 32768, cb1, H1RC,
      (float*)nullptr);

  // coord stage
  hipMemsetAsync(pagg, 0, (size_t)NN * 3 * 4, stream);
  k_edge_gemm<1><<<12500, 256, 0, stream>>>(H1RC, eaF8, rowS, colS,
      W1f8 + 2 * 36864, W2sw + 2 * 16384, cb2, cW3, (const float*)nullptr, ndS, pagg);
  k_pos_final<<<587, 256, 0, stream>>>(pos, mask, pagg, pout_f);
}